// Round 1
// baseline (1365.191 us; speedup 1.0000x reference)
//
#include <hip/hip_runtime.h>
#include <hip/hip_bf16.h>

#define HW 65536

// ---------------- stem: conv1(1->8,k3)+relu -> conv2(8->16,k1)+relu ----------------
__global__ __launch_bounds__(256) void k_stem_front(
    const float* __restrict__ depth,
    const float* __restrict__ cw1, const float* __restrict__ cb1,
    const float* __restrict__ cw2, const float* __restrict__ cb2,
    float* __restrict__ t2) {
  __shared__ float w1[72], b1[8], w2[128], b2[16];
  int t = threadIdx.x;
  if (t < 72)  w1[t] = cw1[t];
  if (t < 8)   b1[t] = cb1[t];
  if (t < 128) w2[t] = cw2[t];
  if (t < 16)  b2[t] = cb2[t];
  __syncthreads();
  int p = blockIdx.x * 256 + t;
  int y = p >> 8, x = p & 255;
  float in9[9];
#pragma unroll
  for (int ky = 0; ky < 3; ky++)
#pragma unroll
    for (int kx = 0; kx < 3; kx++) {
      int yy = y + ky - 1, xx = x + kx - 1;
      bool ok = ((unsigned)yy < 256u) && ((unsigned)xx < 256u);
      in9[ky*3+kx] = ok ? depth[yy*256+xx] : 0.f;
    }
  float t1[8];
#pragma unroll
  for (int o = 0; o < 8; o++) {
    float s = b1[o];
#pragma unroll
    for (int i = 0; i < 9; i++) s += in9[i] * w1[o*9+i];
    t1[o] = fmaxf(s, 0.f);
  }
#pragma unroll
  for (int o = 0; o < 16; o++) {
    float s = b2[o];
#pragma unroll
    for (int ci = 0; ci < 8; ci++) s += t1[ci] * w2[o*8+ci];
    t2[o*HW + p] = fmaxf(s, 0.f);
  }
}

// ---------------- stem: conv3(16->16,k3)+relu -> conv4(16->32,k1) ----------------
__global__ __launch_bounds__(256) void k_stem_back(
    const float* __restrict__ t2,
    const float* __restrict__ cw3, const float* __restrict__ cb3,
    const float* __restrict__ cw4, const float* __restrict__ cb4,
    float* __restrict__ t4) {
  __shared__ __align__(16) float w3s[9*256];   // [tap][o*16+ci]
  __shared__ __align__(16) float w4s[512];
  __shared__ float b3s[16], b4s[32];
  int t = threadIdx.x;
  for (int i = t; i < 2304; i += 256) {
    int oc = i / 9, tap = i - oc*9;
    w3s[tap*256 + oc] = cw3[i];
  }
  for (int i = t; i < 512; i += 256) w4s[i] = cw4[i];
  if (t < 16) b3s[t] = cb3[t];
  if (t < 32) b4s[t] = cb4[t];
  __syncthreads();
  int p = blockIdx.x*256 + t;
  int y = p >> 8, x = p & 255;
  float acc3[16];
#pragma unroll
  for (int o = 0; o < 16; o++) acc3[o] = b3s[o];
#pragma unroll
  for (int tap = 0; tap < 9; tap++) {
    int ky = tap/3 - 1, kx = tap - (tap/3)*3 - 1;
    int yy = y+ky, xx = x+kx;
    bool ok = ((unsigned)yy < 256u) && ((unsigned)xx < 256u);
    int pp = yy*256+xx;
    float v[16];
#pragma unroll
    for (int ci = 0; ci < 16; ci++) v[ci] = ok ? t2[ci*HW + pp] : 0.f;
    const float4* w4p = (const float4*)&w3s[tap*256];
#pragma unroll
    for (int o = 0; o < 16; o++) {
#pragma unroll
      for (int c4 = 0; c4 < 4; c4++) {
        float4 w = w4p[o*4 + c4];
        acc3[o] += v[c4*4+0]*w.x + v[c4*4+1]*w.y + v[c4*4+2]*w.z + v[c4*4+3]*w.w;
      }
    }
  }
#pragma unroll
  for (int o = 0; o < 16; o++) acc3[o] = fmaxf(acc3[o], 0.f);
#pragma unroll
  for (int o = 0; o < 32; o++) {
    float s = b4s[o];
    const float4* wp4 = (const float4*)&w4s[o*16];
#pragma unroll
    for (int c4 = 0; c4 < 4; c4++) {
      float4 w = wp4[c4];
      s += acc3[c4*4+0]*w.x + acc3[c4*4+1]*w.y + acc3[c4*4+2]*w.z + acc3[c4*4+3]*w.w;
    }
    t4[o*HW+p] = s;
  }
}

// ---------------- instance norm stats: one block per channel ----------------
__global__ __launch_bounds__(256) void k_instats(const float* __restrict__ t4,
                                                 float* __restrict__ stats) {
  int c = blockIdx.x;
  const float* src = t4 + c*HW;
  float s = 0.f, ss = 0.f;
  for (int i = threadIdx.x; i < HW; i += 256) { float v = src[i]; s += v; ss += v*v; }
#pragma unroll
  for (int off = 32; off > 0; off >>= 1) {
    s  += __shfl_down(s, off, 64);
    ss += __shfl_down(ss, off, 64);
  }
  __shared__ float sh[8];
  int wid = threadIdx.x >> 6;
  if ((threadIdx.x & 63) == 0) { sh[wid] = s; sh[4+wid] = ss; }
  __syncthreads();
  if (threadIdx.x == 0) {
    float S = sh[0]+sh[1]+sh[2]+sh[3], SS = sh[4]+sh[5]+sh[6]+sh[7];
    float m = S * (1.f/65536.f);
    float var = SS * (1.f/65536.f) - m*m;
    stats[c] = m;
    stats[32+c] = rsqrtf(var + 1e-5f);
  }
}

__global__ __launch_bounds__(256) void k_innorm(
    const float* __restrict__ t4, const float* __restrict__ stats,
    const float* __restrict__ ig, const float* __restrict__ ib,
    float* __restrict__ f) {
  int i = blockIdx.x*256 + threadIdx.x;   // over 524288 float4s
  int c = i >> 14;
  float m = stats[c], rs = stats[32+c];
  float a = rs * ig[c];
  float bb = ib[c] - m*a;
  float4 v = ((const float4*)t4)[i];
  v.x = v.x*a+bb; v.y = v.y*a+bb; v.z = v.z*a+bb; v.w = v.w*a+bb;
  ((float4*)f)[i] = v;
}

// ---------------- rel-pos bias, transposed to [head][key][query] ----------------
__global__ __launch_bounds__(256) void k_bias(const int* __restrict__ rpi,
                                              const float* __restrict__ rpb,
                                              float* __restrict__ biasT) {
  int idx = blockIdx.x*256 + threadIdx.x;   // 2*576*256
  if (idx >= 2*576*256) return;
  int hd = idx / 147456;
  int r = idx - hd*147456;
  int j = r >> 8;
  int qq = r & 255;
  biasT[idx] = rpb[rpi[qq*576 + j]*2 + hd];
}

// ---------------- LN + matmul (q: NC=32, kv: NC=64), one thread per pixel ----------------
template<int NC>
__global__ __launch_bounds__(256) void k_lnmm(
    const float* __restrict__ src, const float* __restrict__ g,
    const float* __restrict__ bln, const float* __restrict__ wmat,
    const float* __restrict__ bout, float* __restrict__ out) {
  __shared__ __align__(16) float ws[32*NC];
  __shared__ float gs[32], bs[32], b2s[NC];
  int t = threadIdx.x;
  for (int i = t; i < 32*NC; i += 256) ws[i] = wmat[i];
  if (t < 32) { gs[t] = g[t]; bs[t] = bln[t]; }
  if (t < NC) b2s[t] = bout[t];
  __syncthreads();
  int p = blockIdx.x*256 + t;
  float v[32]; float s = 0.f;
#pragma unroll
  for (int c = 0; c < 32; c++) { v[c] = src[c*HW+p]; s += v[c]; }
  float m = s * 0.03125f;
  float ss = 0.f;
#pragma unroll
  for (int c = 0; c < 32; c++) { float d = v[c]-m; ss += d*d; }
  float rs = rsqrtf(ss*0.03125f + 1e-5f);
  float acc[NC];
#pragma unroll
  for (int j = 0; j < NC; j++) acc[j] = b2s[j];
#pragma unroll
  for (int c = 0; c < 32; c++) {
    float ln = (v[c]-m)*rs*gs[c] + bs[c];
    const float4* w4 = (const float4*)&ws[c*NC];
#pragma unroll
    for (int j4 = 0; j4 < NC/4; j4++) {
      float4 w = w4[j4];
      acc[j4*4+0] += ln*w.x; acc[j4*4+1] += ln*w.y;
      acc[j4*4+2] += ln*w.z; acc[j4*4+3] += ln*w.w;
    }
  }
#pragma unroll
  for (int j = 0; j < NC; j++) out[j*HW+p] = acc[j];
}

// ---------------- attention: block = (window, head), thread = query ----------------
#define CHUNK 288
__global__ __launch_bounds__(256) void k_attn(
    const float* __restrict__ q, const float* __restrict__ kv,
    const float* __restrict__ biasT, float* __restrict__ ao) {
  __shared__ __align__(16) float kl[CHUNK*16];
  __shared__ __align__(16) float vl[CHUNK*16];
  int wi = blockIdx.x >> 1, hd = blockIdx.x & 1;
  int wy = wi >> 4, wx = wi & 15;
  int t = threadIdx.x;
  int by = wy*16 - 4, bx = wx*16 - 4;
  int kbase = hd*16*HW, vbase = (32 + hd*16)*HW;
  int qy = wy*16 + (t >> 4), qx = wx*16 + (t & 15);
  int p = qy*256 + qx;
  float qr[16];
#pragma unroll
  for (int i = 0; i < 16; i++) qr[i] = q[(hd*16+i)*HW + p] * 0.25f;
  const float* brow = biasT + hd*(576*256) + t;
  float m = -1e30f, l = 0.f;
  float o[16];
#pragma unroll
  for (int i = 0; i < 16; i++) o[i] = 0.f;

  for (int ch = 0; ch < 2; ch++) {
    __syncthreads();
    int j0 = ch * CHUNK;
    for (int e = t; e < CHUNK*16; e += 256) {
      int j = e >> 4, i = e & 15;
      int jg = j0 + j;
      int dy = jg / 24, dx = jg - dy*24;
      int yy = by + dy, xx = bx + dx;
      bool ok = ((unsigned)yy < 256u) && ((unsigned)xx < 256u);
      int pp = yy*256 + xx;
      kl[e] = ok ? kv[kbase + i*HW + pp] : 0.f;
      vl[e] = ok ? kv[vbase + i*HW + pp] : 0.f;
    }
    __syncthreads();
    for (int jj = 0; jj < CHUNK; jj++) {
      const float4* k4 = (const float4*)&kl[jj*16];
      float4 a0 = k4[0], a1 = k4[1], a2 = k4[2], a3 = k4[3];
      float s = brow[(j0 + jj) * 256];
      s += qr[0]*a0.x + qr[1]*a0.y + qr[2]*a0.z + qr[3]*a0.w
         + qr[4]*a1.x + qr[5]*a1.y + qr[6]*a1.z + qr[7]*a1.w
         + qr[8]*a2.x + qr[9]*a2.y + qr[10]*a2.z + qr[11]*a2.w
         + qr[12]*a3.x + qr[13]*a3.y + qr[14]*a3.z + qr[15]*a3.w;
      const float4* v4 = (const float4*)&vl[jj*16];
      float4 b0 = v4[0], b1 = v4[1], b2 = v4[2], b3 = v4[3];
      if (s <= m) {
        float pe = __expf(s - m);
        l += pe;
        o[0]  += pe*b0.x; o[1]  += pe*b0.y; o[2]  += pe*b0.z; o[3]  += pe*b0.w;
        o[4]  += pe*b1.x; o[5]  += pe*b1.y; o[6]  += pe*b1.z; o[7]  += pe*b1.w;
        o[8]  += pe*b2.x; o[9]  += pe*b2.y; o[10] += pe*b2.z; o[11] += pe*b2.w;
        o[12] += pe*b3.x; o[13] += pe*b3.y; o[14] += pe*b3.z; o[15] += pe*b3.w;
      } else {
        float sc = __expf(m - s);
        m = s;
        l = l*sc + 1.f;
        o[0]  = o[0] *sc + b0.x; o[1]  = o[1] *sc + b0.y; o[2]  = o[2] *sc + b0.z; o[3]  = o[3] *sc + b0.w;
        o[4]  = o[4] *sc + b1.x; o[5]  = o[5] *sc + b1.y; o[6]  = o[6] *sc + b1.z; o[7]  = o[7] *sc + b1.w;
        o[8]  = o[8] *sc + b2.x; o[9]  = o[9] *sc + b2.y; o[10] = o[10]*sc + b2.z; o[11] = o[11]*sc + b2.w;
        o[12] = o[12]*sc + b3.x; o[13] = o[13]*sc + b3.y; o[14] = o[14]*sc + b3.z; o[15] = o[15]*sc + b3.w;
      }
    }
  }
  float inv = 1.f / l;
#pragma unroll
  for (int i = 0; i < 16; i++) ao[(hd*16+i)*HW + p] = o[i] * inv;
}

// ---------------- projection + shortcut ----------------
__global__ __launch_bounds__(256) void k_proj(
    const float* __restrict__ ao, const float* __restrict__ wpm,
    const float* __restrict__ bpv, const float* __restrict__ shortcut,
    float* __restrict__ o) {
  __shared__ __align__(16) float ws[1024];
  __shared__ float bs[32];
  int t = threadIdx.x;
  for (int i = t; i < 1024; i += 256) ws[i] = wpm[i];
  if (t < 32) bs[t] = bpv[t];
  __syncthreads();
  int p = blockIdx.x*256 + t;
  float v[32];
#pragma unroll
  for (int c = 0; c < 32; c++) v[c] = ao[c*HW+p];
  float acc[32];
#pragma unroll
  for (int j = 0; j < 32; j++) acc[j] = bs[j];
#pragma unroll
  for (int c = 0; c < 32; c++) {
    float vc = v[c];
    const float4* w4 = (const float4*)&ws[c*32];
#pragma unroll
    for (int j4 = 0; j4 < 8; j4++) {
      float4 w = w4[j4];
      acc[j4*4+0] += vc*w.x; acc[j4*4+1] += vc*w.y;
      acc[j4*4+2] += vc*w.z; acc[j4*4+3] += vc*w.w;
    }
  }
#pragma unroll
  for (int j = 0; j < 32; j++) o[j*HW+p] = acc[j] + shortcut[j*HW+p];
}

// ---------------- MLP (LN -> 32x64 gelu -> 64x32, residual) ----------------
__global__ __launch_bounds__(256) void k_mlp(
    float* __restrict__ o,
    const float* __restrict__ g, const float* __restrict__ b,
    const float* __restrict__ mw1, const float* __restrict__ mb1,
    const float* __restrict__ mw2, const float* __restrict__ mb2) {
  __shared__ __align__(16) float w1s[2048];
  __shared__ __align__(16) float w2s[2048];
  __shared__ float b1s[64], b2s[32], gs[32], bs[32];
  int t = threadIdx.x;
  for (int i = t; i < 2048; i += 256) { w1s[i] = mw1[i]; w2s[i] = mw2[i]; }
  if (t < 64) b1s[t] = mb1[t];
  if (t < 32) { b2s[t] = mb2[t]; gs[t] = g[t]; bs[t] = b[t]; }
  __syncthreads();
  int p = blockIdx.x*256 + t;
  float v[32]; float s = 0.f;
#pragma unroll
  for (int c = 0; c < 32; c++) { v[c] = o[c*HW + p]; s += v[c]; }
  float m = s * 0.03125f;
  float ss = 0.f;
#pragma unroll
  for (int c = 0; c < 32; c++) { float d = v[c] - m; ss += d*d; }
  float rs = rsqrtf(ss * 0.03125f + 1e-5f);
  float h[64];
#pragma unroll
  for (int k = 0; k < 64; k++) h[k] = b1s[k];
#pragma unroll
  for (int c = 0; c < 32; c++) {
    float ln = (v[c] - m) * rs * gs[c] + bs[c];
    const float4* w4 = (const float4*)&w1s[c*64];
#pragma unroll
    for (int k4 = 0; k4 < 16; k4++) {
      float4 w = w4[k4];
      h[k4*4+0] += ln*w.x; h[k4*4+1] += ln*w.y; h[k4*4+2] += ln*w.z; h[k4*4+3] += ln*w.w;
    }
  }
#pragma unroll
  for (int k = 0; k < 64; k++) {
    float xx = h[k];
    float u = 0.7978845608f * (xx + 0.044715f*xx*xx*xx);
    float th = 1.f - 2.f/(1.f + __expf(2.f*u));   // tanh(u)
    h[k] = 0.5f * xx * (1.f + th);
  }
  float r[32];
#pragma unroll
  for (int j = 0; j < 32; j++) r[j] = b2s[j];
#pragma unroll
  for (int k = 0; k < 64; k++) {
    float hk = h[k];
    const float4* w4 = (const float4*)&w2s[k*32];
#pragma unroll
    for (int j4 = 0; j4 < 8; j4++) {
      float4 w = w4[j4];
      r[j4*4+0] += hk*w.x; r[j4*4+1] += hk*w.y; r[j4*4+2] += hk*w.z; r[j4*4+3] += hk*w.w;
    }
  }
#pragma unroll
  for (int j = 0; j < 32; j++) o[j*HW + p] = v[j] + r[j];
}

// ---------------- final: out = o1 + o2 + x (o1 aliases out) ----------------
__global__ __launch_bounds__(256) void k_final(
    const float* o1, const float* __restrict__ o2,
    const float* __restrict__ x, float* out) {
  int i = blockIdx.x*256 + threadIdx.x;
  float4 a = ((const float4*)o1)[i];
  float4 b = ((const float4*)o2)[i];
  float4 c = ((const float4*)x)[i];
  float4 r;
  r.x = a.x + b.x + c.x; r.y = a.y + b.y + c.y;
  r.z = a.z + b.z + c.z; r.w = a.w + b.w + c.w;
  ((float4*)out)[i] = r;
}

extern "C" void kernel_launch(void* const* d_in, const int* in_sizes, int n_in,
                              void* d_out, int out_size, void* d_ws, size_t ws_size,
                              hipStream_t stream) {
  const float* x    = (const float*)d_in[0];
  const float* depth= (const float*)d_in[1];
  const int*   rpi  = (const int*)d_in[2];
  const float* cw1  = (const float*)d_in[3],  *cb1 = (const float*)d_in[4];
  const float* cw2  = (const float*)d_in[5],  *cb2 = (const float*)d_in[6];
  const float* cw3  = (const float*)d_in[7],  *cb3 = (const float*)d_in[8];
  const float* cw4  = (const float*)d_in[9],  *cb4 = (const float*)d_in[10];
  const float* in_g = (const float*)d_in[11], *in_b = (const float*)d_in[12];
  const float* n1g  = (const float*)d_in[13], *n1b = (const float*)d_in[14];
  const float* wq   = (const float*)d_in[15], *bq  = (const float*)d_in[16];
  const float* wkv  = (const float*)d_in[17], *bkv = (const float*)d_in[18];
  const float* rpb  = (const float*)d_in[19];
  const float* wp   = (const float*)d_in[20], *bp  = (const float*)d_in[21];
  const float* n2g  = (const float*)d_in[22], *n2b = (const float*)d_in[23];
  const float* mw1  = (const float*)d_in[24], *mb1 = (const float*)d_in[25];
  const float* mw2  = (const float*)d_in[26], *mb2 = (const float*)d_in[27];

  float* W     = (float*)d_ws;
  float* f     = W;                  // 2,097,152
  float* qb    = W + 2097152;        // 2,097,152
  float* kvb   = W + 4194304;        // 4,194,304
  float* ao    = W + 8388608;        // 2,097,152
  float* o2    = W + 10485760;       // 2,097,152
  float* biasT = W + 12582912;       // 294,912
  float* stats = W + 12877824;       // 64
  float* t2 = qb;                    // stem temps reuse q/kv regions
  float* t4 = kvb;
  float* o1 = (float*)d_out;         // d_out doubles as o1 scratch

  // stem
  k_stem_front<<<256, 256, 0, stream>>>(depth, cw1, cb1, cw2, cb2, t2);
  k_stem_back <<<256, 256, 0, stream>>>(t2, cw3, cb3, cw4, cb4, t4);
  k_instats   <<<32,  256, 0, stream>>>(t4, stats);
  k_innorm    <<<2048,256, 0, stream>>>(t4, stats, in_g, in_b, f);
  k_bias      <<<1152,256, 0, stream>>>(rpi, rpb, biasT);

  // ocab1: q from x, kv from f, shortcut x -> o1
  k_lnmm<32><<<256, 256, 0, stream>>>(x, n1g, n1b, wq, bq, qb);
  k_lnmm<64><<<256, 256, 0, stream>>>(f, n1g, n1b, wkv, bkv, kvb);
  k_attn    <<<512, 256, 0, stream>>>(qb, kvb, biasT, ao);
  k_proj    <<<256, 256, 0, stream>>>(ao, wp, bp, x, o1);
  k_mlp     <<<256, 256, 0, stream>>>(o1, n2g, n2b, mw1, mb1, mw2, mb2);

  // ocab2: q from f, kv from x, shortcut f -> o2
  k_lnmm<32><<<256, 256, 0, stream>>>(f, n1g, n1b, wq, bq, qb);
  k_lnmm<64><<<256, 256, 0, stream>>>(x, n1g, n1b, wkv, bkv, kvb);
  k_attn    <<<512, 256, 0, stream>>>(qb, kvb, biasT, ao);
  k_proj    <<<256, 256, 0, stream>>>(ao, wp, bp, f, o2);
  k_mlp     <<<256, 256, 0, stream>>>(o2, n2g, n2b, mw1, mb1, mw2, mb2);

  // out = o1 + o2 + x
  k_final<<<2048, 256, 0, stream>>>(o1, o2, x, (float*)d_out);
}

// Round 2
// 764.362 us; speedup vs baseline: 1.7861x; 1.7861x over previous
//
#include <hip/hip_runtime.h>
#include <hip/hip_bf16.h>

#define HW 65536

// ---------------- stem: conv1(1->8,k3)+relu -> conv2(8->16,k1)+relu ----------------
__global__ __launch_bounds__(256) void k_stem_front(
    const float* __restrict__ depth,
    const float* __restrict__ cw1, const float* __restrict__ cb1,
    const float* __restrict__ cw2, const float* __restrict__ cb2,
    float* __restrict__ t2) {
  int t = threadIdx.x;
  int p = blockIdx.x * 256 + t;
  int y = p >> 8, x = p & 255;
  float in9[9];
#pragma unroll
  for (int ky = 0; ky < 3; ky++)
#pragma unroll
    for (int kx = 0; kx < 3; kx++) {
      int yy = y + ky - 1, xx = x + kx - 1;
      bool ok = ((unsigned)yy < 256u) && ((unsigned)xx < 256u);
      in9[ky*3+kx] = ok ? depth[yy*256+xx] : 0.f;
    }
  float t1[8];
#pragma unroll
  for (int o = 0; o < 8; o++) {
    float s = cb1[o];                       // uniform -> s_load
#pragma unroll
    for (int i = 0; i < 9; i++) s += in9[i] * cw1[o*9+i];
    t1[o] = fmaxf(s, 0.f);
  }
#pragma unroll
  for (int o = 0; o < 16; o++) {
    float s = cb2[o];
#pragma unroll
    for (int ci = 0; ci < 8; ci++) s += t1[ci] * cw2[o*8+ci];
    t2[o*HW + p] = fmaxf(s, 0.f);
  }
}

// ---------------- conv3 (16->16, k3) + relu: 4 out-ch per thread, weights via SGPR ----------------
__global__ __launch_bounds__(256) void k_conv3(
    const float* __restrict__ t2, const float* __restrict__ cw3,
    const float* __restrict__ cb3, float* __restrict__ t3) {
  int t = threadIdx.x;
  int p = blockIdx.x*256 + t;
  int og = blockIdx.y;                      // 4 output channels per group
  int y = p >> 8, x = p & 255;
  float acc[4];
#pragma unroll
  for (int o = 0; o < 4; o++) acc[o] = cb3[og*4+o];
#pragma unroll 1
  for (int tap = 0; tap < 9; tap++) {
    int ky = tap/3 - 1, kx = tap - (tap/3)*3 - 1;
    int yy = y+ky, xx = x+kx;
    bool ok = ((unsigned)yy < 256u) && ((unsigned)xx < 256u);
    int pp = yy*256+xx;
#pragma unroll
    for (int ci = 0; ci < 16; ci++) {
      float v = ok ? t2[ci*HW+pp] : 0.f;
#pragma unroll
      for (int o = 0; o < 4; o++)
        acc[o] += v * cw3[(og*4+o)*144 + ci*9 + tap];   // uniform index -> s_load
    }
  }
#pragma unroll
  for (int o = 0; o < 4; o++) t3[(og*4+o)*HW+p] = fmaxf(acc[o], 0.f);
}

// ---------------- conv4 (16->32, k1) ----------------
__global__ __launch_bounds__(256) void k_conv4(
    const float* __restrict__ t3, const float* __restrict__ cw4,
    const float* __restrict__ cb4, float* __restrict__ t4) {
  int t = threadIdx.x;
  int p = blockIdx.x*256 + t;
  float v[16];
#pragma unroll
  for (int ci = 0; ci < 16; ci++) v[ci] = t3[ci*HW+p];
#pragma unroll
  for (int o = 0; o < 32; o++) {
    float s = cb4[o];
#pragma unroll
    for (int ci = 0; ci < 16; ci++) s += v[ci]*cw4[o*16+ci];
    t4[o*HW+p] = s;
  }
}

// ---------------- instance norm stats: one block per channel ----------------
__global__ __launch_bounds__(256) void k_instats(const float* __restrict__ t4,
                                                 float* __restrict__ stats) {
  int c = blockIdx.x;
  const float* src = t4 + c*HW;
  float s = 0.f, ss = 0.f;
  for (int i = threadIdx.x; i < HW; i += 256) { float v = src[i]; s += v; ss += v*v; }
#pragma unroll
  for (int off = 32; off > 0; off >>= 1) {
    s  += __shfl_down(s, off, 64);
    ss += __shfl_down(ss, off, 64);
  }
  __shared__ float sh[8];
  int wid = threadIdx.x >> 6;
  if ((threadIdx.x & 63) == 0) { sh[wid] = s; sh[4+wid] = ss; }
  __syncthreads();
  if (threadIdx.x == 0) {
    float S = sh[0]+sh[1]+sh[2]+sh[3], SS = sh[4]+sh[5]+sh[6]+sh[7];
    float m = S * (1.f/65536.f);
    float var = SS * (1.f/65536.f) - m*m;
    stats[c] = m;
    stats[32+c] = rsqrtf(var + 1e-5f);
  }
}

__global__ __launch_bounds__(256) void k_innorm(
    const float* __restrict__ t4, const float* __restrict__ stats,
    const float* __restrict__ ig, const float* __restrict__ ib,
    float* __restrict__ f) {
  int i = blockIdx.x*256 + threadIdx.x;   // over 524288 float4s
  int c = i >> 14;
  float m = stats[c], rs = stats[32+c];
  float a = rs * ig[c];
  float bb = ib[c] - m*a;
  float4 v = ((const float4*)t4)[i];
  v.x = v.x*a+bb; v.y = v.y*a+bb; v.z = v.z*a+bb; v.w = v.w*a+bb;
  ((float4*)f)[i] = v;
}

// ---------------- rel-pos bias, transposed to [head][key][query] ----------------
__global__ __launch_bounds__(256) void k_bias(const int* __restrict__ rpi,
                                              const float* __restrict__ rpb,
                                              float* __restrict__ biasT) {
  int idx = blockIdx.x*256 + threadIdx.x;   // 2*576*256
  if (idx >= 2*576*256) return;
  int hd = idx / 147456;
  int r = idx - hd*147456;
  int j = r >> 8;
  int qq = r & 255;
  biasT[idx] = rpb[rpi[qq*576 + j]*2 + hd];
}

// ---------------- LN + matmul (q: NC=32, kv: NC=64), 32-wide output chunks ----------------
template<int NC>
__global__ __launch_bounds__(256) void k_lnmm(
    const float* __restrict__ src, const float* __restrict__ g,
    const float* __restrict__ bln, const float* __restrict__ wmat,
    const float* __restrict__ bout, float* __restrict__ out) {
  __shared__ __align__(16) float ws[32*NC];
  __shared__ float gs[32], bs[32], b2s[NC];
  int t = threadIdx.x;
  for (int i = t; i < 32*NC; i += 256) ws[i] = wmat[i];
  if (t < 32) { gs[t] = g[t]; bs[t] = bln[t]; }
  if (t < NC) b2s[t] = bout[t];
  __syncthreads();
  int p = blockIdx.x*256 + t;
  float v[32]; float s = 0.f;
#pragma unroll
  for (int c = 0; c < 32; c++) { v[c] = src[c*HW+p]; s += v[c]; }
  float m = s * 0.03125f;
  float ss = 0.f;
#pragma unroll
  for (int c = 0; c < 32; c++) { float d = v[c]-m; ss += d*d; }
  float rs = rsqrtf(ss*0.03125f + 1e-5f);
#pragma unroll 1
  for (int j0 = 0; j0 < NC; j0 += 32) {
    float acc[32];
#pragma unroll
    for (int j = 0; j < 32; j++) acc[j] = b2s[j0+j];
#pragma unroll
    for (int c = 0; c < 32; c++) {
      float ln = (v[c]-m)*rs*gs[c] + bs[c];
      const float4* w4 = (const float4*)&ws[c*NC + j0];
#pragma unroll
      for (int j4 = 0; j4 < 8; j4++) {
        float4 w = w4[j4];
        acc[j4*4+0] += ln*w.x; acc[j4*4+1] += ln*w.y;
        acc[j4*4+2] += ln*w.z; acc[j4*4+3] += ln*w.w;
      }
    }
#pragma unroll
    for (int j = 0; j < 32; j++) out[(j0+j)*HW+p] = acc[j];
  }
}

// ---------------- attention: block = (window, head), thread = query ----------------
#define CHUNK 288
__global__ __launch_bounds__(256) void k_attn(
    const float* __restrict__ q, const float* __restrict__ kv,
    const float* __restrict__ biasT, float* __restrict__ ao) {
  __shared__ __align__(16) float kl[CHUNK*16];
  __shared__ __align__(16) float vl[CHUNK*16];
  int wi = blockIdx.x >> 1, hd = blockIdx.x & 1;
  int wy = wi >> 4, wx = wi & 15;
  int t = threadIdx.x;
  int by = wy*16 - 4, bx = wx*16 - 4;
  int kbase = hd*16*HW, vbase = (32 + hd*16)*HW;
  int qy = wy*16 + (t >> 4), qx = wx*16 + (t & 15);
  int p = qy*256 + qx;
  float qr[16];
#pragma unroll
  for (int i = 0; i < 16; i++) qr[i] = q[(hd*16+i)*HW + p] * 0.25f;
  const float* brow = biasT + hd*(576*256) + t;
  float m = -1e30f, l = 0.f;
  float o[16];
#pragma unroll
  for (int i = 0; i < 16; i++) o[i] = 0.f;

  for (int ch = 0; ch < 2; ch++) {
    __syncthreads();
    int j0 = ch * CHUNK;
    for (int e = t; e < CHUNK*16; e += 256) {
      int j = e >> 4, i = e & 15;
      int jg = j0 + j;
      int dy = jg / 24, dx = jg - dy*24;
      int yy = by + dy, xx = bx + dx;
      bool ok = ((unsigned)yy < 256u) && ((unsigned)xx < 256u);
      int pp = yy*256 + xx;
      kl[e] = ok ? kv[kbase + i*HW + pp] : 0.f;
      vl[e] = ok ? kv[vbase + i*HW + pp] : 0.f;
    }
    __syncthreads();
    for (int jj = 0; jj < CHUNK; jj++) {
      const float4* k4 = (const float4*)&kl[jj*16];
      float4 a0 = k4[0], a1 = k4[1], a2 = k4[2], a3 = k4[3];
      float s = brow[(j0 + jj) * 256];
      s += qr[0]*a0.x + qr[1]*a0.y + qr[2]*a0.z + qr[3]*a0.w
         + qr[4]*a1.x + qr[5]*a1.y + qr[6]*a1.z + qr[7]*a1.w
         + qr[8]*a2.x + qr[9]*a2.y + qr[10]*a2.z + qr[11]*a2.w
         + qr[12]*a3.x + qr[13]*a3.y + qr[14]*a3.z + qr[15]*a3.w;
      const float4* v4 = (const float4*)&vl[jj*16];
      float4 b0 = v4[0], b1 = v4[1], b2 = v4[2], b3 = v4[3];
      if (s <= m) {
        float pe = __expf(s - m);
        l += pe;
        o[0]  += pe*b0.x; o[1]  += pe*b0.y; o[2]  += pe*b0.z; o[3]  += pe*b0.w;
        o[4]  += pe*b1.x; o[5]  += pe*b1.y; o[6]  += pe*b1.z; o[7]  += pe*b1.w;
        o[8]  += pe*b2.x; o[9]  += pe*b2.y; o[10] += pe*b2.z; o[11] += pe*b2.w;
        o[12] += pe*b3.x; o[13] += pe*b3.y; o[14] += pe*b3.z; o[15] += pe*b3.w;
      } else {
        float sc = __expf(m - s);
        m = s;
        l = l*sc + 1.f;
        o[0]  = o[0] *sc + b0.x; o[1]  = o[1] *sc + b0.y; o[2]  = o[2] *sc + b0.z; o[3]  = o[3] *sc + b0.w;
        o[4]  = o[4] *sc + b1.x; o[5]  = o[5] *sc + b1.y; o[6]  = o[6] *sc + b1.z; o[7]  = o[7] *sc + b1.w;
        o[8]  = o[8] *sc + b2.x; o[9]  = o[9] *sc + b2.y; o[10] = o[10]*sc + b2.z; o[11] = o[11]*sc + b2.w;
        o[12] = o[12]*sc + b3.x; o[13] = o[13]*sc + b3.y; o[14] = o[14]*sc + b3.z; o[15] = o[15]*sc + b3.w;
      }
    }
  }
  float inv = 1.f / l;
#pragma unroll
  for (int i = 0; i < 16; i++) ao[(hd*16+i)*HW + p] = o[i] * inv;
}

// ---------------- projection + shortcut ----------------
__global__ __launch_bounds__(256) void k_proj(
    const float* __restrict__ ao, const float* __restrict__ wpm,
    const float* __restrict__ bpv, const float* __restrict__ shortcut,
    float* __restrict__ o) {
  __shared__ __align__(16) float ws[1024];
  __shared__ float bs[32];
  int t = threadIdx.x;
  for (int i = t; i < 1024; i += 256) ws[i] = wpm[i];
  if (t < 32) bs[t] = bpv[t];
  __syncthreads();
  int p = blockIdx.x*256 + t;
  float v[32];
#pragma unroll
  for (int c = 0; c < 32; c++) v[c] = ao[c*HW+p];
  float acc[32];
#pragma unroll
  for (int j = 0; j < 32; j++) acc[j] = bs[j];
#pragma unroll
  for (int c = 0; c < 32; c++) {
    float vc = v[c];
    const float4* w4 = (const float4*)&ws[c*32];
#pragma unroll
    for (int j4 = 0; j4 < 8; j4++) {
      float4 w = w4[j4];
      acc[j4*4+0] += vc*w.x; acc[j4*4+1] += vc*w.y;
      acc[j4*4+2] += vc*w.z; acc[j4*4+3] += vc*w.w;
    }
  }
#pragma unroll
  for (int j = 0; j < 32; j++) o[j*HW+p] = acc[j] + shortcut[j*HW+p];
}

// ---------------- MLP (LN -> 32x64 gelu -> 64x32, residual), hidden in 2 halves ----------------
__global__ __launch_bounds__(256) void k_mlp(
    float* __restrict__ o,
    const float* __restrict__ g, const float* __restrict__ b,
    const float* __restrict__ mw1, const float* __restrict__ mb1,
    const float* __restrict__ mw2, const float* __restrict__ mb2) {
  __shared__ __align__(16) float w1s[2048];
  __shared__ __align__(16) float w2s[2048];
  __shared__ float b1s[64], b2s[32], gs[32], bs[32];
  int t = threadIdx.x;
  for (int i = t; i < 2048; i += 256) { w1s[i] = mw1[i]; w2s[i] = mw2[i]; }
  if (t < 64) b1s[t] = mb1[t];
  if (t < 32) { b2s[t] = mb2[t]; gs[t] = g[t]; bs[t] = b[t]; }
  __syncthreads();
  int p = blockIdx.x*256 + t;
  float v[32]; float s = 0.f;
#pragma unroll
  for (int c = 0; c < 32; c++) { v[c] = o[c*HW + p]; s += v[c]; }
  float m = s * 0.03125f;
  float ss = 0.f;
#pragma unroll
  for (int c = 0; c < 32; c++) { float d = v[c] - m; ss += d*d; }
  float rs = rsqrtf(ss * 0.03125f + 1e-5f);
  float r[32];
#pragma unroll
  for (int j = 0; j < 32; j++) r[j] = b2s[j];
#pragma unroll 1
  for (int half = 0; half < 2; half++) {
    float h[32];
#pragma unroll
    for (int k = 0; k < 32; k++) h[k] = b1s[half*32 + k];
#pragma unroll
    for (int c = 0; c < 32; c++) {
      float ln = (v[c] - m) * rs * gs[c] + bs[c];
      const float4* w4 = (const float4*)&w1s[c*64 + half*32];
#pragma unroll
      for (int k4 = 0; k4 < 8; k4++) {
        float4 w = w4[k4];
        h[k4*4+0] += ln*w.x; h[k4*4+1] += ln*w.y; h[k4*4+2] += ln*w.z; h[k4*4+3] += ln*w.w;
      }
    }
#pragma unroll
    for (int k = 0; k < 32; k++) {
      float xx = h[k];
      float u = 0.7978845608f * (xx + 0.044715f*xx*xx*xx);
      float th = 1.f - 2.f/(1.f + __expf(2.f*u));   // tanh(u)
      h[k] = 0.5f * xx * (1.f + th);
    }
#pragma unroll
    for (int k = 0; k < 32; k++) {
      float hk = h[k];
      const float4* w4 = (const float4*)&w2s[(half*32 + k)*32];
#pragma unroll
      for (int j4 = 0; j4 < 8; j4++) {
        float4 w = w4[j4];
        r[j4*4+0] += hk*w.x; r[j4*4+1] += hk*w.y; r[j4*4+2] += hk*w.z; r[j4*4+3] += hk*w.w;
      }
    }
  }
#pragma unroll
  for (int j = 0; j < 32; j++) o[j*HW + p] = v[j] + r[j];
}

// ---------------- final: out = o1 + o2 + x (o1 aliases out) ----------------
__global__ __launch_bounds__(256) void k_final(
    const float* o1, const float* __restrict__ o2,
    const float* __restrict__ x, float* out) {
  int i = blockIdx.x*256 + threadIdx.x;
  float4 a = ((const float4*)o1)[i];
  float4 b = ((const float4*)o2)[i];
  float4 c = ((const float4*)x)[i];
  float4 r;
  r.x = a.x + b.x + c.x; r.y = a.y + b.y + c.y;
  r.z = a.z + b.z + c.z; r.w = a.w + b.w + c.w;
  ((float4*)out)[i] = r;
}

extern "C" void kernel_launch(void* const* d_in, const int* in_sizes, int n_in,
                              void* d_out, int out_size, void* d_ws, size_t ws_size,
                              hipStream_t stream) {
  const float* x    = (const float*)d_in[0];
  const float* depth= (const float*)d_in[1];
  const int*   rpi  = (const int*)d_in[2];
  const float* cw1  = (const float*)d_in[3],  *cb1 = (const float*)d_in[4];
  const float* cw2  = (const float*)d_in[5],  *cb2 = (const float*)d_in[6];
  const float* cw3  = (const float*)d_in[7],  *cb3 = (const float*)d_in[8];
  const float* cw4  = (const float*)d_in[9],  *cb4 = (const float*)d_in[10];
  const float* in_g = (const float*)d_in[11], *in_b = (const float*)d_in[12];
  const float* n1g  = (const float*)d_in[13], *n1b = (const float*)d_in[14];
  const float* wq   = (const float*)d_in[15], *bq  = (const float*)d_in[16];
  const float* wkv  = (const float*)d_in[17], *bkv = (const float*)d_in[18];
  const float* rpb  = (const float*)d_in[19];
  const float* wp   = (const float*)d_in[20], *bp  = (const float*)d_in[21];
  const float* n2g  = (const float*)d_in[22], *n2b = (const float*)d_in[23];
  const float* mw1  = (const float*)d_in[24], *mb1 = (const float*)d_in[25];
  const float* mw2  = (const float*)d_in[26], *mb2 = (const float*)d_in[27];

  float* W     = (float*)d_ws;
  float* f     = W;                  // 2,097,152
  float* qb    = W + 2097152;        // 2,097,152
  float* kvb   = W + 4194304;        // 4,194,304
  float* ao    = W + 8388608;        // 2,097,152
  float* o2    = W + 10485760;       // 2,097,152
  float* biasT = W + 12582912;       // 294,912
  float* stats = W + 12877824;       // 64
  float* t2 = qb;                    // stem temps reuse q/kv/ao regions
  float* t3 = ao;
  float* t4 = kvb;
  float* o1 = (float*)d_out;         // d_out doubles as o1 scratch

  // stem
  k_stem_front<<<256, 256, 0, stream>>>(depth, cw1, cb1, cw2, cb2, t2);
  k_conv3     <<<dim3(256,4), 256, 0, stream>>>(t2, cw3, cb3, t3);
  k_conv4     <<<256, 256, 0, stream>>>(t3, cw4, cb4, t4);
  k_instats   <<<32,  256, 0, stream>>>(t4, stats);
  k_innorm    <<<2048,256, 0, stream>>>(t4, stats, in_g, in_b, f);
  k_bias      <<<1152,256, 0, stream>>>(rpi, rpb, biasT);

  // ocab1: q from x, kv from f, shortcut x -> o1
  k_lnmm<32><<<256, 256, 0, stream>>>(x, n1g, n1b, wq, bq, qb);
  k_lnmm<64><<<256, 256, 0, stream>>>(f, n1g, n1b, wkv, bkv, kvb);
  k_attn    <<<512, 256, 0, stream>>>(qb, kvb, biasT, ao);
  k_proj    <<<256, 256, 0, stream>>>(ao, wp, bp, x, o1);
  k_mlp     <<<256, 256, 0, stream>>>(o1, n2g, n2b, mw1, mb1, mw2, mb2);

  // ocab2: q from f, kv from x, shortcut f -> o2
  k_lnmm<32><<<256, 256, 0, stream>>>(f, n1g, n1b, wq, bq, qb);
  k_lnmm<64><<<256, 256, 0, stream>>>(x, n1g, n1b, wkv, bkv, kvb);
  k_attn    <<<512, 256, 0, stream>>>(qb, kvb, biasT, ao);
  k_proj    <<<256, 256, 0, stream>>>(ao, wp, bp, f, o2);
  k_mlp     <<<256, 256, 0, stream>>>(o2, n2g, n2b, mw1, mb1, mw2, mb2);

  // out = o1 + o2 + x
  k_final<<<2048, 256, 0, stream>>>(o1, o2, x, (float*)d_out);
}

// Round 3
// 516.346 us; speedup vs baseline: 2.6439x; 1.4803x over previous
//
#include <hip/hip_runtime.h>
#include <hip/hip_bf16.h>

#define HW 65536
#define KPAD 584   // Vt row stride (bf16 elems): 584*2=1168B = 73*16 -> aligned, conflict-free
#define PROW 40    // P scratch row stride (bf16 elems): 80B rows -> 2-way (free) on b128 re-read

typedef __attribute__((ext_vector_type(8))) short bf8;
typedef __attribute__((ext_vector_type(4))) float f4;

__device__ inline unsigned short f2b(float x) {   // RNE float->bf16
  unsigned int u = __float_as_uint(x);
  unsigned int r = (u + 0x7fff + ((u >> 16) & 1)) >> 16;
  return (unsigned short)r;
}

// ---------------- stem: conv1(1->8,k3)+relu -> conv2(8->16,k1)+relu ----------------
__global__ __launch_bounds__(256) void k_stem_front(
    const float* __restrict__ depth,
    const float* __restrict__ cw1, const float* __restrict__ cb1,
    const float* __restrict__ cw2, const float* __restrict__ cb2,
    float* __restrict__ t2) {
  int t = threadIdx.x;
  int p = blockIdx.x * 256 + t;
  int y = p >> 8, x = p & 255;
  float in9[9];
#pragma unroll
  for (int ky = 0; ky < 3; ky++)
#pragma unroll
    for (int kx = 0; kx < 3; kx++) {
      int yy = y + ky - 1, xx = x + kx - 1;
      bool ok = ((unsigned)yy < 256u) && ((unsigned)xx < 256u);
      in9[ky*3+kx] = ok ? depth[yy*256+xx] : 0.f;
    }
  float t1[8];
#pragma unroll
  for (int o = 0; o < 8; o++) {
    float s = cb1[o];
#pragma unroll
    for (int i = 0; i < 9; i++) s += in9[i] * cw1[o*9+i];
    t1[o] = fmaxf(s, 0.f);
  }
#pragma unroll
  for (int o = 0; o < 16; o++) {
    float s = cb2[o];
#pragma unroll
    for (int ci = 0; ci < 8; ci++) s += t1[ci] * cw2[o*8+ci];
    t2[o*HW + p] = fmaxf(s, 0.f);
  }
}

// ---------------- conv3 (16->16, k3) + relu: 4 out-ch per thread, weights via SGPR ----------------
__global__ __launch_bounds__(256) void k_conv3(
    const float* __restrict__ t2, const float* __restrict__ cw3,
    const float* __restrict__ cb3, float* __restrict__ t3) {
  int t = threadIdx.x;
  int p = blockIdx.x*256 + t;
  int og = blockIdx.y;
  int y = p >> 8, x = p & 255;
  float acc[4];
#pragma unroll
  for (int o = 0; o < 4; o++) acc[o] = cb3[og*4+o];
#pragma unroll 1
  for (int tap = 0; tap < 9; tap++) {
    int ky = tap/3 - 1, kx = tap - (tap/3)*3 - 1;
    int yy = y+ky, xx = x+kx;
    bool ok = ((unsigned)yy < 256u) && ((unsigned)xx < 256u);
    int pp = yy*256+xx;
#pragma unroll
    for (int ci = 0; ci < 16; ci++) {
      float v = ok ? t2[ci*HW+pp] : 0.f;
#pragma unroll
      for (int o = 0; o < 4; o++)
        acc[o] += v * cw3[(og*4+o)*144 + ci*9 + tap];
    }
  }
#pragma unroll
  for (int o = 0; o < 4; o++) t3[(og*4+o)*HW+p] = fmaxf(acc[o], 0.f);
}

// ---------------- conv4 (16->32, k1) ----------------
__global__ __launch_bounds__(256) void k_conv4(
    const float* __restrict__ t3, const float* __restrict__ cw4,
    const float* __restrict__ cb4, float* __restrict__ t4) {
  int t = threadIdx.x;
  int p = blockIdx.x*256 + t;
  float v[16];
#pragma unroll
  for (int ci = 0; ci < 16; ci++) v[ci] = t3[ci*HW+p];
#pragma unroll
  for (int o = 0; o < 32; o++) {
    float s = cb4[o];
#pragma unroll
    for (int ci = 0; ci < 16; ci++) s += v[ci]*cw4[o*16+ci];
    t4[o*HW+p] = s;
  }
}

// ---------------- instance norm stats ----------------
__global__ __launch_bounds__(256) void k_instats(const float* __restrict__ t4,
                                                 float* __restrict__ stats) {
  int c = blockIdx.x;
  const float* src = t4 + c*HW;
  float s = 0.f, ss = 0.f;
  for (int i = threadIdx.x; i < HW; i += 256) { float v = src[i]; s += v; ss += v*v; }
#pragma unroll
  for (int off = 32; off > 0; off >>= 1) {
    s  += __shfl_down(s, off, 64);
    ss += __shfl_down(ss, off, 64);
  }
  __shared__ float sh[8];
  int wid = threadIdx.x >> 6;
  if ((threadIdx.x & 63) == 0) { sh[wid] = s; sh[4+wid] = ss; }
  __syncthreads();
  if (threadIdx.x == 0) {
    float S = sh[0]+sh[1]+sh[2]+sh[3], SS = sh[4]+sh[5]+sh[6]+sh[7];
    float m = S * (1.f/65536.f);
    float var = SS * (1.f/65536.f) - m*m;
    stats[c] = m;
    stats[32+c] = rsqrtf(var + 1e-5f);
  }
}

__global__ __launch_bounds__(256) void k_innorm(
    const float* __restrict__ t4, const float* __restrict__ stats,
    const float* __restrict__ ig, const float* __restrict__ ib,
    float* __restrict__ f) {
  int i = blockIdx.x*256 + threadIdx.x;
  int c = i >> 14;
  float m = stats[c], rs = stats[32+c];
  float a = rs * ig[c];
  float bb = ib[c] - m*a;
  float4 v = ((const float4*)t4)[i];
  v.x = v.x*a+bb; v.y = v.y*a+bb; v.z = v.z*a+bb; v.w = v.w*a+bb;
  ((float4*)f)[i] = v;
}

// ---------------- rel-pos bias, transposed [head][key][query], with softmax shift folded ----------------
__global__ __launch_bounds__(256) void k_bias(const int* __restrict__ rpi,
                                              const float* __restrict__ rpb,
                                              float* __restrict__ biasT) {
  int idx = blockIdx.x*256 + threadIdx.x;   // 2*576*256
  if (idx >= 2*576*256) return;
  int hd = idx / 147456;
  int r = idx - hd*147456;
  int j = r >> 8;
  int qq = r & 255;
  biasT[idx] = rpb[rpi[qq*576 + j]*2 + hd] - 8.0f;  // -8: fixed softmax shift (scores bounded; cancels in normalize)
}

// ---------------- LN + matmul (q: NC=32, kv: NC=64) ----------------
template<int NC>
__global__ __launch_bounds__(256) void k_lnmm(
    const float* __restrict__ src, const float* __restrict__ g,
    const float* __restrict__ bln, const float* __restrict__ wmat,
    const float* __restrict__ bout, float* __restrict__ out) {
  __shared__ __align__(16) float ws[32*NC];
  __shared__ float gs[32], bs[32], b2s[NC];
  int t = threadIdx.x;
  for (int i = t; i < 32*NC; i += 256) ws[i] = wmat[i];
  if (t < 32) { gs[t] = g[t]; bs[t] = bln[t]; }
  if (t < NC) b2s[t] = bout[t];
  __syncthreads();
  int p = blockIdx.x*256 + t;
  float v[32]; float s = 0.f;
#pragma unroll
  for (int c = 0; c < 32; c++) { v[c] = src[c*HW+p]; s += v[c]; }
  float m = s * 0.03125f;
  float ss = 0.f;
#pragma unroll
  for (int c = 0; c < 32; c++) { float d = v[c]-m; ss += d*d; }
  float rs = rsqrtf(ss*0.03125f + 1e-5f);
#pragma unroll 1
  for (int j0 = 0; j0 < NC; j0 += 32) {
    float acc[32];
#pragma unroll
    for (int j = 0; j < 32; j++) acc[j] = b2s[j0+j];
#pragma unroll
    for (int c = 0; c < 32; c++) {
      float ln = (v[c]-m)*rs*gs[c] + bs[c];
      const float4* w4 = (const float4*)&ws[c*NC + j0];
#pragma unroll
      for (int j4 = 0; j4 < 8; j4++) {
        float4 w = w4[j4];
        acc[j4*4+0] += ln*w.x; acc[j4*4+1] += ln*w.y;
        acc[j4*4+2] += ln*w.z; acc[j4*4+3] += ln*w.w;
      }
    }
#pragma unroll
    for (int j = 0; j < 32; j++) out[(j0+j)*HW+p] = acc[j];
  }
}

// ---------------- MFMA attention: block = (window, head), 4 waves x 4 q-tiles ----------------
__global__ __launch_bounds__(256) void k_attn(
    const float* __restrict__ q, const float* __restrict__ kv,
    const float* __restrict__ biasT, float* __restrict__ ao) {
  __shared__ __align__(16) unsigned short Qs[256*16];   // [q][d] bf16, q pre-scaled 0.25
  __shared__ __align__(16) unsigned short Ks[576*16];   // [key][d]
  __shared__ __align__(16) unsigned short Vt[16*KPAD];  // [d][key]
  __shared__ __align__(16) unsigned short Ps[4][16*PROW]; // per-wave P scratch [q][32key]

  int wi = blockIdx.x >> 1, hd = blockIdx.x & 1;
  int wy = wi >> 4, wx = wi & 15;
  int t = threadIdx.x;
  int by = wy*16 - 4, bx = wx*16 - 4;
  int kbase = hd*16*HW, vbase = (32 + hd*16)*HW;

  // --- stage Q: thread t = query row t (row-major in window)
  {
    int qy = wy*16 + (t >> 4), qx = wx*16 + (t & 15);
    int p = qy*256 + qx;
    unsigned short tmp[16];
#pragma unroll
    for (int i = 0; i < 16; i++) tmp[i] = f2b(q[(hd*16+i)*HW + p] * 0.25f);
    *(uint4*)&Qs[t*16]     = *(uint4*)&tmp[0];
    *(uint4*)&Qs[t*16 + 8] = *(uint4*)&tmp[8];
  }
  // --- stage K (row-major [key][d]) and V (transposed [d][key])
  for (int e = t; e < 576; e += 256) {
    int dy = e / 24, dx = e - dy*24;
    int yy = by + dy, xx = bx + dx;
    bool ok = ((unsigned)yy < 256u) && ((unsigned)xx < 256u);
    int pp = yy*256 + xx;
    unsigned short tk[16];
#pragma unroll
    for (int i = 0; i < 16; i++) {
      float kvl = ok ? kv[kbase + i*HW + pp] : 0.f;
      float vvl = ok ? kv[vbase + i*HW + pp] : 0.f;
      tk[i] = f2b(kvl);
      Vt[i*KPAD + e] = f2b(vvl);
    }
    *(uint4*)&Ks[e*16]     = *(uint4*)&tk[0];
    *(uint4*)&Ks[e*16 + 8] = *(uint4*)&tk[8];
  }
  __syncthreads();

  int wave = t >> 6, lane = t & 63;
  int quad = lane >> 4, l16 = lane & 15;
  const bf8 zero8 = {0,0,0,0,0,0,0,0};
  unsigned short* Pw = &Ps[wave][0];

#pragma unroll 1
  for (int qi = 0; qi < 4; qi++) {
    int qt = wave + qi*4;              // q-tile 0..15
    bf8 qf = zero8;
    if (quad < 2) qf = *(const bf8*)&Qs[(qt*16 + l16)*16 + quad*8];
    f4 oacc = {0.f, 0.f, 0.f, 0.f};
    float lr[4] = {0.f, 0.f, 0.f, 0.f};
    const float* bbase = biasT + hd*147456 + qt*16 + quad*4;

#pragma unroll 1
    for (int kt2 = 0; kt2 < 18; kt2++) {
      int k0 = kt2 * 32;
      bf8 kf0 = zero8, kf1 = zero8;
      if (quad < 2) {
        kf0 = *(const bf8*)&Ks[(k0 + l16)*16 + quad*8];
        kf1 = *(const bf8*)&Ks[(k0 + 16 + l16)*16 + quad*8];
      }
      f4 zf = {0.f, 0.f, 0.f, 0.f};
      f4 s0 = __builtin_amdgcn_mfma_f32_16x16x32_bf16(qf, kf0, zf, 0, 0, 0);
      f4 s1 = __builtin_amdgcn_mfma_f32_16x16x32_bf16(qf, kf1, zf, 0, 0, 0);
      f4 b0 = *(const f4*)&bbase[(k0 + l16)*256];
      f4 b1 = *(const f4*)&bbase[(k0 + 16 + l16)*256];
      float p0[4], p1[4];
#pragma unroll
      for (int r = 0; r < 4; r++) {
        p0[r] = __expf(s0[r] + b0[r]);
        p1[r] = __expf(s1[r] + b1[r]);
        lr[r] += p0[r] + p1[r];
      }
#pragma unroll
      for (int r = 0; r < 4; r++) {
        Pw[(quad*4 + r)*PROW + l16]      = f2b(p0[r]);
        Pw[(quad*4 + r)*PROW + 16 + l16] = f2b(p1[r]);
      }
      __asm__ __volatile__("s_waitcnt lgkmcnt(0)" ::: "memory");
      bf8 pf = *(const bf8*)&Pw[l16*PROW + quad*8];
      bf8 vf = *(const bf8*)&Vt[l16*KPAD + k0 + quad*8];
      oacc = __builtin_amdgcn_mfma_f32_16x16x32_bf16(pf, vf, oacc, 0, 0, 0);
    }
    // row sums across the 16 lanes of each quad
#pragma unroll
    for (int r = 0; r < 4; r++) {
#pragma unroll
      for (int off = 1; off < 16; off <<= 1) lr[r] += __shfl_xor(lr[r], off, 64);
    }
    // write O: lane holds O[q=quad*4+r][d=l16]
#pragma unroll
    for (int r = 0; r < 4; r++) {
      int qw = qt*16 + quad*4 + r;
      int qy = wy*16 + (qw >> 4), qx = wx*16 + (qw & 15);
      ao[(hd*16 + l16)*HW + qy*256 + qx] = oacc[r] / lr[r];
    }
  }
}

// ---------------- projection + shortcut ----------------
__global__ __launch_bounds__(256) void k_proj(
    const float* __restrict__ ao, const float* __restrict__ wpm,
    const float* __restrict__ bpv, const float* __restrict__ shortcut,
    float* __restrict__ o) {
  __shared__ __align__(16) float ws[1024];
  __shared__ float bs[32];
  int t = threadIdx.x;
  for (int i = t; i < 1024; i += 256) ws[i] = wpm[i];
  if (t < 32) bs[t] = bpv[t];
  __syncthreads();
  int p = blockIdx.x*256 + t;
  float v[32];
#pragma unroll
  for (int c = 0; c < 32; c++) v[c] = ao[c*HW+p];
  float acc[32];
#pragma unroll
  for (int j = 0; j < 32; j++) acc[j] = bs[j];
#pragma unroll
  for (int c = 0; c < 32; c++) {
    float vc = v[c];
    const float4* w4 = (const float4*)&ws[c*32];
#pragma unroll
    for (int j4 = 0; j4 < 8; j4++) {
      float4 w = w4[j4];
      acc[j4*4+0] += vc*w.x; acc[j4*4+1] += vc*w.y;
      acc[j4*4+2] += vc*w.z; acc[j4*4+3] += vc*w.w;
    }
  }
#pragma unroll
  for (int j = 0; j < 32; j++) o[j*HW+p] = acc[j] + shortcut[j*HW+p];
}

// ---------------- MLP (LN -> 32x64 gelu -> 64x32, residual), hidden in 2 halves ----------------
__global__ __launch_bounds__(256) void k_mlp(
    float* __restrict__ o,
    const float* __restrict__ g, const float* __restrict__ b,
    const float* __restrict__ mw1, const float* __restrict__ mb1,
    const float* __restrict__ mw2, const float* __restrict__ mb2) {
  __shared__ __align__(16) float w1s[2048];
  __shared__ __align__(16) float w2s[2048];
  __shared__ float b1s[64], b2s[32], gs[32], bs[32];
  int t = threadIdx.x;
  for (int i = t; i < 2048; i += 256) { w1s[i] = mw1[i]; w2s[i] = mw2[i]; }
  if (t < 64) b1s[t] = mb1[t];
  if (t < 32) { b2s[t] = mb2[t]; gs[t] = g[t]; bs[t] = b[t]; }
  __syncthreads();
  int p = blockIdx.x*256 + t;
  float v[32]; float s = 0.f;
#pragma unroll
  for (int c = 0; c < 32; c++) { v[c] = o[c*HW + p]; s += v[c]; }
  float m = s * 0.03125f;
  float ss = 0.f;
#pragma unroll
  for (int c = 0; c < 32; c++) { float d = v[c] - m; ss += d*d; }
  float rs = rsqrtf(ss * 0.03125f + 1e-5f);
  float r[32];
#pragma unroll
  for (int j = 0; j < 32; j++) r[j] = b2s[j];
#pragma unroll 1
  for (int half = 0; half < 2; half++) {
    float h[32];
#pragma unroll
    for (int k = 0; k < 32; k++) h[k] = b1s[half*32 + k];
#pragma unroll
    for (int c = 0; c < 32; c++) {
      float ln = (v[c] - m) * rs * gs[c] + bs[c];
      const float4* w4 = (const float4*)&w1s[c*64 + half*32];
#pragma unroll
      for (int k4 = 0; k4 < 8; k4++) {
        float4 w = w4[k4];
        h[k4*4+0] += ln*w.x; h[k4*4+1] += ln*w.y; h[k4*4+2] += ln*w.z; h[k4*4+3] += ln*w.w;
      }
    }
#pragma unroll
    for (int k = 0; k < 32; k++) {
      float xx = h[k];
      float u = 0.7978845608f * (xx + 0.044715f*xx*xx*xx);
      float th = 1.f - 2.f/(1.f + __expf(2.f*u));
      h[k] = 0.5f * xx * (1.f + th);
    }
#pragma unroll
    for (int k = 0; k < 32; k++) {
      float hk = h[k];
      const float4* w4 = (const float4*)&w2s[(half*32 + k)*32];
#pragma unroll
      for (int j4 = 0; j4 < 8; j4++) {
        float4 w = w4[j4];
        r[j4*4+0] += hk*w.x; r[j4*4+1] += hk*w.y; r[j4*4+2] += hk*w.z; r[j4*4+3] += hk*w.w;
      }
    }
  }
#pragma unroll
  for (int j = 0; j < 32; j++) o[j*HW + p] = v[j] + r[j];
}

// ---------------- final: out = o1 + o2 + x (o1 aliases out) ----------------
__global__ __launch_bounds__(256) void k_final(
    const float* o1, const float* __restrict__ o2,
    const float* __restrict__ x, float* out) {
  int i = blockIdx.x*256 + threadIdx.x;
  float4 a = ((const float4*)o1)[i];
  float4 b = ((const float4*)o2)[i];
  float4 c = ((const float4*)x)[i];
  float4 r;
  r.x = a.x + b.x + c.x; r.y = a.y + b.y + c.y;
  r.z = a.z + b.z + c.z; r.w = a.w + b.w + c.w;
  ((float4*)out)[i] = r;
}

extern "C" void kernel_launch(void* const* d_in, const int* in_sizes, int n_in,
                              void* d_out, int out_size, void* d_ws, size_t ws_size,
                              hipStream_t stream) {
  const float* x    = (const float*)d_in[0];
  const float* depth= (const float*)d_in[1];
  const int*   rpi  = (const int*)d_in[2];
  const float* cw1  = (const float*)d_in[3],  *cb1 = (const float*)d_in[4];
  const float* cw2  = (const float*)d_in[5],  *cb2 = (const float*)d_in[6];
  const float* cw3  = (const float*)d_in[7],  *cb3 = (const float*)d_in[8];
  const float* cw4  = (const float*)d_in[9],  *cb4 = (const float*)d_in[10];
  const float* in_g = (const float*)d_in[11], *in_b = (const float*)d_in[12];
  const float* n1g  = (const float*)d_in[13], *n1b = (const float*)d_in[14];
  const float* wq   = (const float*)d_in[15], *bq  = (const float*)d_in[16];
  const float* wkv  = (const float*)d_in[17], *bkv = (const float*)d_in[18];
  const float* rpb  = (const float*)d_in[19];
  const float* wp   = (const float*)d_in[20], *bp  = (const float*)d_in[21];
  const float* n2g  = (const float*)d_in[22], *n2b = (const float*)d_in[23];
  const float* mw1  = (const float*)d_in[24], *mb1 = (const float*)d_in[25];
  const float* mw2  = (const float*)d_in[26], *mb2 = (const float*)d_in[27];

  float* W     = (float*)d_ws;
  float* f     = W;                  // 2,097,152
  float* qb    = W + 2097152;        // 2,097,152
  float* kvb   = W + 4194304;        // 4,194,304
  float* ao    = W + 8388608;        // 2,097,152
  float* o2    = W + 10485760;       // 2,097,152
  float* biasT = W + 12582912;       // 294,912
  float* stats = W + 12877824;       // 64
  float* t2 = qb;
  float* t3 = ao;
  float* t4 = kvb;
  float* o1 = (float*)d_out;

  // stem
  k_stem_front<<<256, 256, 0, stream>>>(depth, cw1, cb1, cw2, cb2, t2);
  k_conv3     <<<dim3(256,4), 256, 0, stream>>>(t2, cw3, cb3, t3);
  k_conv4     <<<256, 256, 0, stream>>>(t3, cw4, cb4, t4);
  k_instats   <<<32,  256, 0, stream>>>(t4, stats);
  k_innorm    <<<2048,256, 0, stream>>>(t4, stats, in_g, in_b, f);
  k_bias      <<<1152,256, 0, stream>>>(rpi, rpb, biasT);

  // ocab1: q from x, kv from f, shortcut x -> o1
  k_lnmm<32><<<256, 256, 0, stream>>>(x, n1g, n1b, wq, bq, qb);
  k_lnmm<64><<<256, 256, 0, stream>>>(f, n1g, n1b, wkv, bkv, kvb);
  k_attn    <<<512, 256, 0, stream>>>(qb, kvb, biasT, ao);
  k_proj    <<<256, 256, 0, stream>>>(ao, wp, bp, x, o1);
  k_mlp     <<<256, 256, 0, stream>>>(o1, n2g, n2b, mw1, mb1, mw2, mb2);

  // ocab2: q from f, kv from x, shortcut f -> o2
  k_lnmm<32><<<256, 256, 0, stream>>>(f, n1g, n1b, wq, bq, qb);
  k_lnmm<64><<<256, 256, 0, stream>>>(x, n1g, n1b, wkv, bkv, kvb);
  k_attn    <<<512, 256, 0, stream>>>(qb, kvb, biasT, ao);
  k_proj    <<<256, 256, 0, stream>>>(ao, wp, bp, f, o2);
  k_mlp     <<<256, 256, 0, stream>>>(o2, n2g, n2b, mw1, mb1, mw2, mb2);

  // out = o1 + o2 + x
  k_final<<<2048, 256, 0, stream>>>(o1, o2, x, (float*)d_out);
}

// Round 4
// 437.987 us; speedup vs baseline: 3.1170x; 1.1789x over previous
//
#include <hip/hip_runtime.h>
#include <hip/hip_bf16.h>

#define HW 65536
#define KPAD 584   // Vt row stride (bf16): 1168B rows, 16B-aligned; 2 accesses/bank = free
#define PROW 40    // P scratch row stride (bf16): 80B rows -> 2-way (free) on b128 re-read

typedef __attribute__((ext_vector_type(8))) short bf8;
typedef __attribute__((ext_vector_type(4))) float f4;

__device__ inline unsigned short f2b(float x) {   // RNE float->bf16
  unsigned int u = __float_as_uint(x);
  unsigned int r = (u + 0x7fff + ((u >> 16) & 1)) >> 16;
  return (unsigned short)r;
}

// ---------------- stem: conv1(1->8,k3)+relu -> conv2(8->16,k1)+relu ----------------
__global__ __launch_bounds__(256) void k_stem_front(
    const float* __restrict__ depth,
    const float* __restrict__ cw1, const float* __restrict__ cb1,
    const float* __restrict__ cw2, const float* __restrict__ cb2,
    float* __restrict__ t2) {
  int t = threadIdx.x;
  int p = blockIdx.x * 256 + t;
  int y = p >> 8, x = p & 255;
  float in9[9];
#pragma unroll
  for (int ky = 0; ky < 3; ky++)
#pragma unroll
    for (int kx = 0; kx < 3; kx++) {
      int yy = y + ky - 1, xx = x + kx - 1;
      bool ok = ((unsigned)yy < 256u) && ((unsigned)xx < 256u);
      in9[ky*3+kx] = ok ? depth[yy*256+xx] : 0.f;
    }
  float t1[8];
#pragma unroll
  for (int o = 0; o < 8; o++) {
    float s = cb1[o];
#pragma unroll
    for (int i = 0; i < 9; i++) s += in9[i] * cw1[o*9+i];
    t1[o] = fmaxf(s, 0.f);
  }
#pragma unroll
  for (int o = 0; o < 16; o++) {
    float s = cb2[o];
#pragma unroll
    for (int ci = 0; ci < 8; ci++) s += t1[ci] * cw2[o*8+ci];
    t2[o*HW + p] = fmaxf(s, 0.f);
  }
}

// ---------------- conv3 (16->16, k3) + relu: 4 out-ch per thread, weights via SGPR ----------------
__global__ __launch_bounds__(256) void k_conv3(
    const float* __restrict__ t2, const float* __restrict__ cw3,
    const float* __restrict__ cb3, float* __restrict__ t3) {
  int t = threadIdx.x;
  int p = blockIdx.x*256 + t;
  int og = blockIdx.y;
  int y = p >> 8, x = p & 255;
  float acc[4];
#pragma unroll
  for (int o = 0; o < 4; o++) acc[o] = cb3[og*4+o];
#pragma unroll 1
  for (int tap = 0; tap < 9; tap++) {
    int ky = tap/3 - 1, kx = tap - (tap/3)*3 - 1;
    int yy = y+ky, xx = x+kx;
    bool ok = ((unsigned)yy < 256u) && ((unsigned)xx < 256u);
    int pp = yy*256+xx;
#pragma unroll
    for (int ci = 0; ci < 16; ci++) {
      float v = ok ? t2[ci*HW+pp] : 0.f;
#pragma unroll
      for (int o = 0; o < 4; o++)
        acc[o] += v * cw3[(og*4+o)*144 + ci*9 + tap];
    }
  }
#pragma unroll
  for (int o = 0; o < 4; o++) t3[(og*4+o)*HW+p] = fmaxf(acc[o], 0.f);
}

// ---------------- conv4 (16->32, k1) ----------------
__global__ __launch_bounds__(256) void k_conv4(
    const float* __restrict__ t3, const float* __restrict__ cw4,
    const float* __restrict__ cb4, float* __restrict__ t4) {
  int t = threadIdx.x;
  int p = blockIdx.x*256 + t;
  float v[16];
#pragma unroll
  for (int ci = 0; ci < 16; ci++) v[ci] = t3[ci*HW+p];
#pragma unroll
  for (int o = 0; o < 32; o++) {
    float s = cb4[o];
#pragma unroll
    for (int ci = 0; ci < 16; ci++) s += v[ci]*cw4[o*16+ci];
    t4[o*HW+p] = s;
  }
}

// ---------------- instance norm stats, two-stage ----------------
__global__ __launch_bounds__(256) void k_instats1(const float* __restrict__ t4,
                                                  float* __restrict__ part) {
  int c = blockIdx.x >> 3, seg = blockIdx.x & 7;   // 256 blocks: 8 segments per channel
  const float4* src = (const float4*)(t4 + c*HW + seg*8192);
  float s = 0.f, ss = 0.f;
  for (int i = threadIdx.x; i < 2048; i += 256) {
    float4 v = src[i];
    s  += v.x + v.y + v.z + v.w;
    ss += v.x*v.x + v.y*v.y + v.z*v.z + v.w*v.w;
  }
#pragma unroll
  for (int off = 32; off > 0; off >>= 1) {
    s  += __shfl_down(s, off, 64);
    ss += __shfl_down(ss, off, 64);
  }
  __shared__ float sh[8];
  int wid = threadIdx.x >> 6;
  if ((threadIdx.x & 63) == 0) { sh[wid] = s; sh[4+wid] = ss; }
  __syncthreads();
  if (threadIdx.x == 0) {
    part[blockIdx.x]       = sh[0]+sh[1]+sh[2]+sh[3];
    part[256 + blockIdx.x] = sh[4]+sh[5]+sh[6]+sh[7];
  }
}

__global__ __launch_bounds__(64) void k_instats2(const float* __restrict__ part,
                                                 float* __restrict__ stats) {
  int c = threadIdx.x;
  if (c < 32) {
    float s = 0.f, ss = 0.f;
#pragma unroll
    for (int k = 0; k < 8; k++) { s += part[c*8+k]; ss += part[256 + c*8+k]; }
    float m = s * (1.f/65536.f);
    float var = ss * (1.f/65536.f) - m*m;
    stats[c] = m;
    stats[32+c] = rsqrtf(var + 1e-5f);
  }
}

__global__ __launch_bounds__(256) void k_innorm(
    const float* __restrict__ t4, const float* __restrict__ stats,
    const float* __restrict__ ig, const float* __restrict__ ib,
    float* __restrict__ f) {
  int i = blockIdx.x*256 + threadIdx.x;
  int c = i >> 14;
  float m = stats[c], rs = stats[32+c];
  float a = rs * ig[c];
  float bb = ib[c] - m*a;
  float4 v = ((const float4*)t4)[i];
  v.x = v.x*a+bb; v.y = v.y*a+bb; v.z = v.z*a+bb; v.w = v.w*a+bb;
  ((float4*)f)[i] = v;
}

// ---------------- rel-pos bias: [head][qtile][key][q16] (MFMA-coalesced), shift folded ----------------
__global__ __launch_bounds__(256) void k_bias(const int* __restrict__ rpi,
                                              const float* __restrict__ rpb,
                                              float* __restrict__ biasT) {
  int idx = blockIdx.x*256 + threadIdx.x;   // 2*16*576*16 = 294912
  if (idx >= 294912) return;
  int hd = idx / 147456;
  int rem = idx - hd*147456;
  int qt = rem / 9216;
  int rem2 = rem - qt*9216;
  int key = rem2 >> 4;
  int q16 = rem2 & 15;
  int q = qt*16 + q16;
  biasT[idx] = rpb[rpi[q*576 + key]*2 + hd] - 8.0f;  // -8: fixed softmax shift, cancels in normalize
}

// ---------------- LN + matmul (q: NC=32, kv: NC=64) ----------------
template<int NC>
__global__ __launch_bounds__(256) void k_lnmm(
    const float* __restrict__ src, const float* __restrict__ g,
    const float* __restrict__ bln, const float* __restrict__ wmat,
    const float* __restrict__ bout, float* __restrict__ out) {
  __shared__ __align__(16) float ws[32*NC];
  __shared__ float gs[32], bs[32], b2s[NC];
  int t = threadIdx.x;
  for (int i = t; i < 32*NC; i += 256) ws[i] = wmat[i];
  if (t < 32) { gs[t] = g[t]; bs[t] = bln[t]; }
  if (t < NC) b2s[t] = bout[t];
  __syncthreads();
  int p = blockIdx.x*256 + t;
  float v[32]; float s = 0.f;
#pragma unroll
  for (int c = 0; c < 32; c++) { v[c] = src[c*HW+p]; s += v[c]; }
  float m = s * 0.03125f;
  float ss = 0.f;
#pragma unroll
  for (int c = 0; c < 32; c++) { float d = v[c]-m; ss += d*d; }
  float rs = rsqrtf(ss*0.03125f + 1e-5f);
#pragma unroll 1
  for (int j0 = 0; j0 < NC; j0 += 32) {
    float acc[32];
#pragma unroll
    for (int j = 0; j < 32; j++) acc[j] = b2s[j0+j];
#pragma unroll
    for (int c = 0; c < 32; c++) {
      float ln = (v[c]-m)*rs*gs[c] + bs[c];
      const float4* w4 = (const float4*)&ws[c*NC + j0];
#pragma unroll
      for (int j4 = 0; j4 < 8; j4++) {
        float4 w = w4[j4];
        acc[j4*4+0] += ln*w.x; acc[j4*4+1] += ln*w.y;
        acc[j4*4+2] += ln*w.z; acc[j4*4+3] += ln*w.w;
      }
    }
#pragma unroll
    for (int j = 0; j < 32; j++) out[(j0+j)*HW+p] = acc[j];
  }
}

// ---------------- MFMA attention: block = (window, head), 4 waves x 4 q-tiles ----------------
__global__ __launch_bounds__(256) void k_attn(
    const float* __restrict__ q, const float* __restrict__ kv,
    const float* __restrict__ biasT, float* __restrict__ ao) {
  __shared__ __align__(16) unsigned short Qs[256*16];      // [q][d] bf16, q pre-scaled 0.25
  __shared__ __align__(16) unsigned short Ks[576*16];      // [key][d]
  __shared__ __align__(16) unsigned short Vt[16*KPAD];     // [d][key]
  __shared__ __align__(16) unsigned short Ps[4][2][16*PROW]; // per-wave double-buffered P

  int wi = blockIdx.x >> 1, hd = blockIdx.x & 1;
  int wy = wi >> 4, wx = wi & 15;
  int t = threadIdx.x;
  int by = wy*16 - 4, bx = wx*16 - 4;
  int kbase = hd*16*HW, vbase = (32 + hd*16)*HW;

  // --- stage Q: thread t = query row t (row-major in window)
  {
    int qy = wy*16 + (t >> 4), qx = wx*16 + (t & 15);
    int p = qy*256 + qx;
    unsigned short tmp[16];
#pragma unroll
    for (int i = 0; i < 16; i++) tmp[i] = f2b(q[(hd*16+i)*HW + p] * 0.25f);
    *(uint4*)&Qs[t*16]     = *(uint4*)&tmp[0];
    *(uint4*)&Qs[t*16 + 8] = *(uint4*)&tmp[8];
  }
  // --- stage K (row-major [key][d]) and V (transposed [d][key])
  for (int e = t; e < 576; e += 256) {
    int dy = e / 24, dx = e - dy*24;
    int yy = by + dy, xx = bx + dx;
    bool ok = ((unsigned)yy < 256u) && ((unsigned)xx < 256u);
    int pp = yy*256 + xx;
    unsigned short tk[16];
#pragma unroll
    for (int i = 0; i < 16; i++) {
      float kvl = ok ? kv[kbase + i*HW + pp] : 0.f;
      float vvl = ok ? kv[vbase + i*HW + pp] : 0.f;
      tk[i] = f2b(kvl);
      Vt[i*KPAD + e] = f2b(vvl);
    }
    *(uint4*)&Ks[e*16]     = *(uint4*)&tk[0];
    *(uint4*)&Ks[e*16 + 8] = *(uint4*)&tk[8];
  }
  __syncthreads();

  int wave = t >> 6, lane = t & 63;
  int quad = lane >> 4, l16 = lane & 15;
  const bf8 zero8 = {0,0,0,0,0,0,0,0};
  const f4 zf = {0.f, 0.f, 0.f, 0.f};

#pragma unroll 1
  for (int qi = 0; qi < 4; qi++) {
    int qt = wave + qi*4;              // q-tile 0..15
    bf8 qf = zero8;
    if (quad < 2) qf = *(const bf8*)&Qs[(qt*16 + l16)*16 + quad*8];
    f4 oacc = {0.f, 0.f, 0.f, 0.f};
    float lr[4] = {0.f, 0.f, 0.f, 0.f};
    // coalesced bias: [head][qt][key][q16]; wave covers contiguous 1KB per load
    const float* bbase = biasT + (hd*16 + qt)*9216 + quad*4;
    f4 bc0 = *(const f4*)&bbase[l16*16];
    f4 bc1 = *(const f4*)&bbase[(16 + l16)*16];

#pragma unroll 2
    for (int kt2 = 0; kt2 < 18; kt2++) {
      int k0 = kt2 * 32;
      f4 bn0 = zf, bn1 = zf;                 // prefetch next k-step's bias
      if (kt2 < 17) {
        bn0 = *(const f4*)&bbase[(k0 + 32 + l16)*16];
        bn1 = *(const f4*)&bbase[(k0 + 48 + l16)*16];
      }
      bf8 kf0 = zero8, kf1 = zero8;
      if (quad < 2) {
        kf0 = *(const bf8*)&Ks[(k0 + l16)*16 + quad*8];
        kf1 = *(const bf8*)&Ks[(k0 + 16 + l16)*16 + quad*8];
      }
      f4 s0 = __builtin_amdgcn_mfma_f32_16x16x32_bf16(qf, kf0, zf, 0, 0, 0);
      f4 s1 = __builtin_amdgcn_mfma_f32_16x16x32_bf16(qf, kf1, zf, 0, 0, 0);
      float p0[4], p1[4];
#pragma unroll
      for (int r = 0; r < 4; r++) {
        p0[r] = __expf(s0[r] + bc0[r]);
        p1[r] = __expf(s1[r] + bc1[r]);
        lr[r] += p0[r] + p1[r];
      }
      unsigned short* Pw = &Ps[wave][kt2 & 1][0];
#pragma unroll
      for (int r = 0; r < 4; r++) {
        Pw[(quad*4 + r)*PROW + l16]      = f2b(p0[r]);
        Pw[(quad*4 + r)*PROW + 16 + l16] = f2b(p1[r]);
      }
      bf8 pf = *(const bf8*)&Pw[l16*PROW + quad*8];
      bf8 vf = *(const bf8*)&Vt[l16*KPAD + k0 + quad*8];
      oacc = __builtin_amdgcn_mfma_f32_16x16x32_bf16(pf, vf, oacc, 0, 0, 0);
      bc0 = bn0; bc1 = bn1;
    }
    // row sums across the 16 lanes of each quad
#pragma unroll
    for (int r = 0; r < 4; r++) {
#pragma unroll
      for (int off = 1; off < 16; off <<= 1) lr[r] += __shfl_xor(lr[r], off, 64);
    }
    // write O: lane holds O[q=quad*4+r][d=l16]
#pragma unroll
    for (int r = 0; r < 4; r++) {
      int qw = qt*16 + quad*4 + r;
      int qy = wy*16 + (qw >> 4), qx = wx*16 + (qw & 15);
      ao[(hd*16 + l16)*HW + qy*256 + qx] = oacc[r] / lr[r];
    }
  }
}

// ---------------- projection + shortcut ----------------
__global__ __launch_bounds__(256) void k_proj(
    const float* __restrict__ ao, const float* __restrict__ wpm,
    const float* __restrict__ bpv, const float* __restrict__ shortcut,
    float* __restrict__ o) {
  __shared__ __align__(16) float ws[1024];
  __shared__ float bs[32];
  int t = threadIdx.x;
  for (int i = t; i < 1024; i += 256) ws[i] = wpm[i];
  if (t < 32) bs[t] = bpv[t];
  __syncthreads();
  int p = blockIdx.x*256 + t;
  float v[32];
#pragma unroll
  for (int c = 0; c < 32; c++) v[c] = ao[c*HW+p];
  float acc[32];
#pragma unroll
  for (int j = 0; j < 32; j++) acc[j] = bs[j];
#pragma unroll
  for (int c = 0; c < 32; c++) {
    float vc = v[c];
    const float4* w4 = (const float4*)&ws[c*32];
#pragma unroll
    for (int j4 = 0; j4 < 8; j4++) {
      float4 w = w4[j4];
      acc[j4*4+0] += vc*w.x; acc[j4*4+1] += vc*w.y;
      acc[j4*4+2] += vc*w.z; acc[j4*4+3] += vc*w.w;
    }
  }
#pragma unroll
  for (int j = 0; j < 32; j++) o[j*HW+p] = acc[j] + shortcut[j*HW+p];
}

// ---------------- MLP (LN -> 32x64 gelu -> 64x32, residual), hidden in 2 halves ----------------
__global__ __launch_bounds__(256) void k_mlp(
    float* __restrict__ o,
    const float* __restrict__ g, const float* __restrict__ b,
    const float* __restrict__ mw1, const float* __restrict__ mb1,
    const float* __restrict__ mw2, const float* __restrict__ mb2) {
  __shared__ __align__(16) float w1s[2048];
  __shared__ __align__(16) float w2s[2048];
  __shared__ float b1s[64], b2s[32], gs[32], bs[32];
  int t = threadIdx.x;
  for (int i = t; i < 2048; i += 256) { w1s[i] = mw1[i]; w2s[i] = mw2[i]; }
  if (t < 64) b1s[t] = mb1[t];
  if (t < 32) { b2s[t] = mb2[t]; gs[t] = g[t]; bs[t] = b[t]; }
  __syncthreads();
  int p = blockIdx.x*256 + t;
  float v[32]; float s = 0.f;
#pragma unroll
  for (int c = 0; c < 32; c++) { v[c] = o[c*HW + p]; s += v[c]; }
  float m = s * 0.03125f;
  float ss = 0.f;
#pragma unroll
  for (int c = 0; c < 32; c++) { float d = v[c] - m; ss += d*d; }
  float rs = rsqrtf(ss * 0.03125f + 1e-5f);
  float r[32];
#pragma unroll
  for (int j = 0; j < 32; j++) r[j] = b2s[j];
#pragma unroll 1
  for (int half = 0; half < 2; half++) {
    float h[32];
#pragma unroll
    for (int k = 0; k < 32; k++) h[k] = b1s[half*32 + k];
#pragma unroll
    for (int c = 0; c < 32; c++) {
      float ln = (v[c] - m) * rs * gs[c] + bs[c];
      const float4* w4 = (const float4*)&w1s[c*64 + half*32];
#pragma unroll
      for (int k4 = 0; k4 < 8; k4++) {
        float4 w = w4[k4];
        h[k4*4+0] += ln*w.x; h[k4*4+1] += ln*w.y; h[k4*4+2] += ln*w.z; h[k4*4+3] += ln*w.w;
      }
    }
#pragma unroll
    for (int k = 0; k < 32; k++) {
      float xx = h[k];
      float u = 0.7978845608f * (xx + 0.044715f*xx*xx*xx);
      float th = 1.f - 2.f/(1.f + __expf(2.f*u));
      h[k] = 0.5f * xx * (1.f + th);
    }
#pragma unroll
    for (int k = 0; k < 32; k++) {
      float hk = h[k];
      const float4* w4 = (const float4*)&w2s[(half*32 + k)*32];
#pragma unroll
      for (int j4 = 0; j4 < 8; j4++) {
        float4 w = w4[j4];
        r[j4*4+0] += hk*w.x; r[j4*4+1] += hk*w.y; r[j4*4+2] += hk*w.z; r[j4*4+3] += hk*w.w;
      }
    }
  }
#pragma unroll
  for (int j = 0; j < 32; j++) o[j*HW + p] = v[j] + r[j];
}

// ---------------- final: out = o1 + o2 + x (o1 aliases out) ----------------
__global__ __launch_bounds__(256) void k_final(
    const float* o1, const float* __restrict__ o2,
    const float* __restrict__ x, float* out) {
  int i = blockIdx.x*256 + threadIdx.x;
  float4 a = ((const float4*)o1)[i];
  float4 b = ((const float4*)o2)[i];
  float4 c = ((const float4*)x)[i];
  float4 r;
  r.x = a.x + b.x + c.x; r.y = a.y + b.y + c.y;
  r.z = a.z + b.z + c.z; r.w = a.w + b.w + c.w;
  ((float4*)out)[i] = r;
}

extern "C" void kernel_launch(void* const* d_in, const int* in_sizes, int n_in,
                              void* d_out, int out_size, void* d_ws, size_t ws_size,
                              hipStream_t stream) {
  const float* x    = (const float*)d_in[0];
  const float* depth= (const float*)d_in[1];
  const int*   rpi  = (const int*)d_in[2];
  const float* cw1  = (const float*)d_in[3],  *cb1 = (const float*)d_in[4];
  const float* cw2  = (const float*)d_in[5],  *cb2 = (const float*)d_in[6];
  const float* cw3  = (const float*)d_in[7],  *cb3 = (const float*)d_in[8];
  const float* cw4  = (const float*)d_in[9],  *cb4 = (const float*)d_in[10];
  const float* in_g = (const float*)d_in[11], *in_b = (const float*)d_in[12];
  const float* n1g  = (const float*)d_in[13], *n1b = (const float*)d_in[14];
  const float* wq   = (const float*)d_in[15], *bq  = (const float*)d_in[16];
  const float* wkv  = (const float*)d_in[17], *bkv = (const float*)d_in[18];
  const float* rpb  = (const float*)d_in[19];
  const float* wp   = (const float*)d_in[20], *bp  = (const float*)d_in[21];
  const float* n2g  = (const float*)d_in[22], *n2b = (const float*)d_in[23];
  const float* mw1  = (const float*)d_in[24], *mb1 = (const float*)d_in[25];
  const float* mw2  = (const float*)d_in[26], *mb2 = (const float*)d_in[27];

  float* W     = (float*)d_ws;
  float* f     = W;                  // 2,097,152
  float* qb    = W + 2097152;        // 2,097,152
  float* kvb   = W + 4194304;        // 4,194,304
  float* ao    = W + 8388608;        // 2,097,152
  float* o2    = W + 10485760;       // 2,097,152
  float* biasT = W + 12582912;       // 294,912
  float* stats = W + 12877824;       // 64
  float* part  = W + 12877888;       // 512
  float* t2 = qb;
  float* t3 = ao;
  float* t4 = kvb;
  float* o1 = (float*)d_out;

  // stem
  k_stem_front<<<256, 256, 0, stream>>>(depth, cw1, cb1, cw2, cb2, t2);
  k_conv3     <<<dim3(256,4), 256, 0, stream>>>(t2, cw3, cb3, t3);
  k_conv4     <<<256, 256, 0, stream>>>(t3, cw4, cb4, t4);
  k_instats1  <<<256, 256, 0, stream>>>(t4, part);
  k_instats2  <<<1,   64,  0, stream>>>(part, stats);
  k_innorm    <<<2048,256, 0, stream>>>(t4, stats, in_g, in_b, f);
  k_bias      <<<1152,256, 0, stream>>>(rpi, rpb, biasT);

  // ocab1: q from x, kv from f, shortcut x -> o1
  k_lnmm<32><<<256, 256, 0, stream>>>(x, n1g, n1b, wq, bq, qb);
  k_lnmm<64><<<256, 256, 0, stream>>>(f, n1g, n1b, wkv, bkv, kvb);
  k_attn    <<<512, 256, 0, stream>>>(qb, kvb, biasT, ao);
  k_proj    <<<256, 256, 0, stream>>>(ao, wp, bp, x, o1);
  k_mlp     <<<256, 256, 0, stream>>>(o1, n2g, n2b, mw1, mb1, mw2, mb2);

  // ocab2: q from f, kv from x, shortcut f -> o2
  k_lnmm<32><<<256, 256, 0, stream>>>(f, n1g, n1b, wq, bq, qb);
  k_lnmm<64><<<256, 256, 0, stream>>>(x, n1g, n1b, wkv, bkv, kvb);
  k_attn    <<<512, 256, 0, stream>>>(qb, kvb, biasT, ao);
  k_proj    <<<256, 256, 0, stream>>>(ao, wp, bp, f, o2);
  k_mlp     <<<256, 256, 0, stream>>>(o2, n2g, n2b, mw1, mb1, mw2, mb2);

  // out = o1 + o2 + x
  k_final<<<2048, 256, 0, stream>>>(o1, o2, x, (float*)d_out);
}

// Round 5
// 323.605 us; speedup vs baseline: 4.2187x; 1.3535x over previous
//
#include <hip/hip_runtime.h>
#include <hip/hip_bf16.h>

#define HW 65536
#define KPAD 584   // Vt row stride (bf16): 1168B rows, 16B-aligned, 2-way bank (free)
#define PROW 40    // P scratch row stride (bf16): 80B rows -> 2-way (free) on b128 re-read

typedef __attribute__((ext_vector_type(8))) short bf8;
typedef __attribute__((ext_vector_type(4))) float f4;

__device__ inline unsigned short f2b(float x) {   // RNE float->bf16
  unsigned int u = __float_as_uint(x);
  unsigned int r = (u + 0x7fff + ((u >> 16) & 1)) >> 16;
  return (unsigned short)r;
}

// ---------------- stem: conv1(1->8,k3)+relu -> conv2(8->16,k1)+relu ----------------
__global__ __launch_bounds__(256) void k_stem_front(
    const float* __restrict__ depth,
    const float* __restrict__ cw1, const float* __restrict__ cb1,
    const float* __restrict__ cw2, const float* __restrict__ cb2,
    float* __restrict__ t2) {
  int t = threadIdx.x;
  int p = blockIdx.x * 256 + t;
  int y = p >> 8, x = p & 255;
  float in9[9];
#pragma unroll
  for (int ky = 0; ky < 3; ky++)
#pragma unroll
    for (int kx = 0; kx < 3; kx++) {
      int yy = y + ky - 1, xx = x + kx - 1;
      bool ok = ((unsigned)yy < 256u) && ((unsigned)xx < 256u);
      in9[ky*3+kx] = ok ? depth[yy*256+xx] : 0.f;
    }
  float t1[8];
#pragma unroll
  for (int o = 0; o < 8; o++) {
    float s = cb1[o];
#pragma unroll
    for (int i = 0; i < 9; i++) s += in9[i] * cw1[o*9+i];
    t1[o] = fmaxf(s, 0.f);
  }
#pragma unroll
  for (int o = 0; o < 16; o++) {
    float s = cb2[o];
#pragma unroll
    for (int ci = 0; ci < 8; ci++) s += t1[ci] * cw2[o*8+ci];
    t2[o*HW + p] = fmaxf(s, 0.f);
  }
}

// ---------------- conv3 (16->16, k3) + relu ----------------
__global__ __launch_bounds__(256) void k_conv3(
    const float* __restrict__ t2, const float* __restrict__ cw3,
    const float* __restrict__ cb3, float* __restrict__ t3) {
  int t = threadIdx.x;
  int p = blockIdx.x*256 + t;
  int og = blockIdx.y;
  int y = p >> 8, x = p & 255;
  float acc[4];
#pragma unroll
  for (int o = 0; o < 4; o++) acc[o] = cb3[og*4+o];
#pragma unroll 1
  for (int tap = 0; tap < 9; tap++) {
    int ky = tap/3 - 1, kx = tap - (tap/3)*3 - 1;
    int yy = y+ky, xx = x+kx;
    bool ok = ((unsigned)yy < 256u) && ((unsigned)xx < 256u);
    int pp = yy*256+xx;
#pragma unroll
    for (int ci = 0; ci < 16; ci++) {
      float v = ok ? t2[ci*HW+pp] : 0.f;
#pragma unroll
      for (int o = 0; o < 4; o++)
        acc[o] += v * cw3[(og*4+o)*144 + ci*9 + tap];
    }
  }
#pragma unroll
  for (int o = 0; o < 4; o++) t3[(og*4+o)*HW+p] = fmaxf(acc[o], 0.f);
}

// ---------------- conv4 (16->32, k1) ----------------
__global__ __launch_bounds__(256) void k_conv4(
    const float* __restrict__ t3, const float* __restrict__ cw4,
    const float* __restrict__ cb4, float* __restrict__ t4) {
  int t = threadIdx.x;
  int p = blockIdx.x*256 + t;
  float v[16];
#pragma unroll
  for (int ci = 0; ci < 16; ci++) v[ci] = t3[ci*HW+p];
#pragma unroll
  for (int o = 0; o < 32; o++) {
    float s = cb4[o];
#pragma unroll
    for (int ci = 0; ci < 16; ci++) s += v[ci]*cw4[o*16+ci];
    t4[o*HW+p] = s;
  }
}

// ---------------- instance norm stats, two-stage ----------------
__global__ __launch_bounds__(256) void k_instats1(const float* __restrict__ t4,
                                                  float* __restrict__ part) {
  int c = blockIdx.x >> 3, seg = blockIdx.x & 7;
  const float4* src = (const float4*)(t4 + c*HW + seg*8192);
  float s = 0.f, ss = 0.f;
  for (int i = threadIdx.x; i < 2048; i += 256) {
    float4 v = src[i];
    s  += v.x + v.y + v.z + v.w;
    ss += v.x*v.x + v.y*v.y + v.z*v.z + v.w*v.w;
  }
#pragma unroll
  for (int off = 32; off > 0; off >>= 1) {
    s  += __shfl_down(s, off, 64);
    ss += __shfl_down(ss, off, 64);
  }
  __shared__ float sh[8];
  int wid = threadIdx.x >> 6;
  if ((threadIdx.x & 63) == 0) { sh[wid] = s; sh[4+wid] = ss; }
  __syncthreads();
  if (threadIdx.x == 0) {
    part[blockIdx.x]       = sh[0]+sh[1]+sh[2]+sh[3];
    part[256 + blockIdx.x] = sh[4]+sh[5]+sh[6]+sh[7];
  }
}

__global__ __launch_bounds__(64) void k_instats2(const float* __restrict__ part,
                                                 float* __restrict__ stats) {
  int c = threadIdx.x;
  if (c < 32) {
    float s = 0.f, ss = 0.f;
#pragma unroll
    for (int k = 0; k < 8; k++) { s += part[c*8+k]; ss += part[256 + c*8+k]; }
    float m = s * (1.f/65536.f);
    float var = ss * (1.f/65536.f) - m*m;
    stats[c] = m;
    stats[32+c] = rsqrtf(var + 1e-5f);
  }
}

// ---------------- rel-pos bias: [head][qtile][key][q16], -8 softmax shift folded ----------------
__global__ __launch_bounds__(256) void k_bias(const int* __restrict__ rpi,
                                              const float* __restrict__ rpb,
                                              float* __restrict__ biasT) {
  int idx = blockIdx.x*256 + threadIdx.x;   // 2*16*576*16 = 294912
  if (idx >= 294912) return;
  int hd = idx / 147456;
  int rem = idx - hd*147456;
  int qt = rem / 9216;
  int rem2 = rem - qt*9216;
  int key = rem2 >> 4;
  int q16 = rem2 & 15;
  int q = qt*16 + q16;
  biasT[idx] = rpb[rpi[q*576 + key]*2 + hd] - 8.0f;
}

// ---------------- LN(+optional IN) + 32x32 matmul slab ----------------
// slabs: 0: q1 = LN(x)@wq          1: kv1[0:32] = LN(IN(t4))@wkv[:,0:32]
//        2: kv1[32:64] (wkv cols 32:64)   3: q2 = LN(IN(t4))@wq
//        4: kv2[0:32] = LN(x)@wkv[:,0:32] 5: kv2[32:64]
__global__ __launch_bounds__(256) void k_lnmm6(
    const float* __restrict__ x, const float* __restrict__ t4,
    const float* __restrict__ stats,
    const float* __restrict__ ig, const float* __restrict__ ib,
    const float* __restrict__ n1g, const float* __restrict__ n1b,
    const float* __restrict__ wq, const float* __restrict__ bq,
    const float* __restrict__ wkv, const float* __restrict__ bkv,
    float* __restrict__ q1, float* __restrict__ kv1,
    float* __restrict__ q2, float* __restrict__ kv2, int ybase) {
  int slab = blockIdx.y + ybase;
  const float* src; const float* wm; const float* bo; float* dst;
  int wstride, coff; bool apply_in;
  switch (slab) {
    default:
    case 0: src=x;  wm=wq;  bo=bq;  dst=q1;         wstride=32; coff=0;  apply_in=false; break;
    case 1: src=t4; wm=wkv; bo=bkv; dst=kv1;        wstride=64; coff=0;  apply_in=true;  break;
    case 2: src=t4; wm=wkv; bo=bkv; dst=kv1+32*HW;  wstride=64; coff=32; apply_in=true;  break;
    case 3: src=t4; wm=wq;  bo=bq;  dst=q2;         wstride=32; coff=0;  apply_in=true;  break;
    case 4: src=x;  wm=wkv; bo=bkv; dst=kv2;        wstride=64; coff=0;  apply_in=false; break;
    case 5: src=x;  wm=wkv; bo=bkv; dst=kv2+32*HW;  wstride=64; coff=32; apply_in=false; break;
  }
  __shared__ __align__(16) float ws[1024];
  __shared__ float gs[32], bs[32], b2s[32], as[32], bbs[32];
  int t = threadIdx.x;
  for (int i = t; i < 1024; i += 256) {
    int c = i >> 5, j = i & 31;
    ws[i] = wm[c*wstride + coff + j];
  }
  if (t < 32) {
    gs[t] = n1g[t]; bs[t] = n1b[t]; b2s[t] = bo[coff+t];
    float a = stats[32+t]*ig[t];
    as[t] = a; bbs[t] = ib[t] - stats[t]*a;
  }
  __syncthreads();
  int p = blockIdx.x*256 + t;
  float v[32]; float s = 0.f;
  if (apply_in) {
#pragma unroll
    for (int c = 0; c < 32; c++) { v[c] = src[c*HW+p]*as[c] + bbs[c]; s += v[c]; }
  } else {
#pragma unroll
    for (int c = 0; c < 32; c++) { v[c] = src[c*HW+p]; s += v[c]; }
  }
  float m = s * 0.03125f;
  float ss = 0.f;
#pragma unroll
  for (int c = 0; c < 32; c++) { float d = v[c]-m; ss += d*d; }
  float rs = rsqrtf(ss*0.03125f + 1e-5f);
  float acc[32];
#pragma unroll
  for (int j = 0; j < 32; j++) acc[j] = b2s[j];
#pragma unroll
  for (int c = 0; c < 32; c++) {
    float ln = (v[c]-m)*rs*gs[c] + bs[c];
    const float4* w4 = (const float4*)&ws[c*32];
#pragma unroll
    for (int j4 = 0; j4 < 8; j4++) {
      float4 w = w4[j4];
      acc[j4*4+0] += ln*w.x; acc[j4*4+1] += ln*w.y;
      acc[j4*4+2] += ln*w.z; acc[j4*4+3] += ln*w.w;
    }
  }
#pragma unroll
  for (int j = 0; j < 32; j++) dst[j*HW+p] = acc[j];
}

// ---------------- MFMA attention: grid (512, nOcab); block=(window,head) ----------------
__global__ __launch_bounds__(256) void k_attn(
    const float* __restrict__ qA, const float* __restrict__ kvA, float* __restrict__ aoA,
    const float* __restrict__ qB, const float* __restrict__ kvB, float* __restrict__ aoB,
    const float* __restrict__ biasT) {
  __shared__ __align__(16) unsigned short Qs[256*16];
  __shared__ __align__(16) unsigned short Ks[576*16];
  __shared__ __align__(16) unsigned short Vt[16*KPAD];
  __shared__ __align__(16) unsigned short Ps[4][16*PROW];   // single-buffer, wave-private

  const float* q  = blockIdx.y ? qB  : qA;
  const float* kv = blockIdx.y ? kvB : kvA;
  float* ao       = blockIdx.y ? aoB : aoA;

  int wi = blockIdx.x >> 1, hd = blockIdx.x & 1;
  int wy = wi >> 4, wx = wi & 15;
  int t = threadIdx.x;
  int by = wy*16 - 4, bx = wx*16 - 4;
  int kbase = hd*16*HW, vbase = (32 + hd*16)*HW;

  {
    int qy = wy*16 + (t >> 4), qx = wx*16 + (t & 15);
    int p = qy*256 + qx;
    unsigned short tmp[16];
#pragma unroll
    for (int i = 0; i < 16; i++) tmp[i] = f2b(q[(hd*16+i)*HW + p] * 0.25f);
    *(uint4*)&Qs[t*16]     = *(uint4*)&tmp[0];
    *(uint4*)&Qs[t*16 + 8] = *(uint4*)&tmp[8];
  }
  for (int e = t; e < 576; e += 256) {
    int dy = e / 24, dx = e - dy*24;
    int yy = by + dy, xx = bx + dx;
    bool ok = ((unsigned)yy < 256u) && ((unsigned)xx < 256u);
    int pp = yy*256 + xx;
    unsigned short tk[16];
#pragma unroll
    for (int i = 0; i < 16; i++) {
      float kvl = ok ? kv[kbase + i*HW + pp] : 0.f;
      float vvl = ok ? kv[vbase + i*HW + pp] : 0.f;
      tk[i] = f2b(kvl);
      Vt[i*KPAD + e] = f2b(vvl);
    }
    *(uint4*)&Ks[e*16]     = *(uint4*)&tk[0];
    *(uint4*)&Ks[e*16 + 8] = *(uint4*)&tk[8];
  }
  __syncthreads();

  int wave = t >> 6, lane = t & 63;
  int quad = lane >> 4, l16 = lane & 15;
  const bf8 zero8 = {0,0,0,0,0,0,0,0};
  const f4 zf = {0.f, 0.f, 0.f, 0.f};
  unsigned short* Pw = &Ps[wave][0];

#pragma unroll 1
  for (int qi = 0; qi < 4; qi++) {
    int qt = wave + qi*4;
    bf8 qf = zero8;
    if (quad < 2) qf = *(const bf8*)&Qs[(qt*16 + l16)*16 + quad*8];
    f4 oacc = {0.f, 0.f, 0.f, 0.f};
    float lr[4] = {0.f, 0.f, 0.f, 0.f};
    const float* bbase = biasT + (hd*16 + qt)*9216 + quad*4;
    f4 bc0 = *(const f4*)&bbase[l16*16];
    f4 bc1 = *(const f4*)&bbase[(16 + l16)*16];

#pragma unroll 2
    for (int kt2 = 0; kt2 < 18; kt2++) {
      int k0 = kt2 * 32;
      f4 bn0 = zf, bn1 = zf;
      if (kt2 < 17) {
        bn0 = *(const f4*)&bbase[(k0 + 32 + l16)*16];
        bn1 = *(const f4*)&bbase[(k0 + 48 + l16)*16];
      }
      bf8 kf0 = zero8, kf1 = zero8;
      if (quad < 2) {
        kf0 = *(const bf8*)&Ks[(k0 + l16)*16 + quad*8];
        kf1 = *(const bf8*)&Ks[(k0 + 16 + l16)*16 + quad*8];
      }
      // bias folded into the MFMA C operand (layout matches C: row=q, col=key)
      f4 s0 = __builtin_amdgcn_mfma_f32_16x16x32_bf16(qf, kf0, bc0, 0, 0, 0);
      f4 s1 = __builtin_amdgcn_mfma_f32_16x16x32_bf16(qf, kf1, bc1, 0, 0, 0);
      float p0[4], p1[4];
#pragma unroll
      for (int r = 0; r < 4; r++) {
        p0[r] = __expf(s0[r]);
        p1[r] = __expf(s1[r]);
        lr[r] += p0[r] + p1[r];
      }
#pragma unroll
      for (int r = 0; r < 4; r++) {
        Pw[(quad*4 + r)*PROW + l16]      = f2b(p0[r]);
        Pw[(quad*4 + r)*PROW + 16 + l16] = f2b(p1[r]);
      }
      bf8 pf = *(const bf8*)&Pw[l16*PROW + quad*8];
      bf8 vf = *(const bf8*)&Vt[l16*KPAD + k0 + quad*8];
      oacc = __builtin_amdgcn_mfma_f32_16x16x32_bf16(pf, vf, oacc, 0, 0, 0);
      bc0 = bn0; bc1 = bn1;
    }
#pragma unroll
    for (int r = 0; r < 4; r++) {
#pragma unroll
      for (int off = 1; off < 16; off <<= 1) lr[r] += __shfl_xor(lr[r], off, 64);
    }
#pragma unroll
    for (int r = 0; r < 4; r++) {
      int qw = qt*16 + quad*4 + r;
      int qy = wy*16 + (qw >> 4), qx = wx*16 + (qw & 15);
      ao[(hd*16 + l16)*HW + qy*256 + qx] = oacc[r] / lr[r];
    }
  }
}

// ---------------- fused projection + shortcut + LN + MLP + residual ----------------
__global__ __launch_bounds__(256) void k_projmlp(
    const float* __restrict__ ao1, const float* __restrict__ ao2,
    const float* __restrict__ x, const float* __restrict__ t4,
    const float* __restrict__ stats,
    const float* __restrict__ ig, const float* __restrict__ ib,
    const float* __restrict__ wp, const float* __restrict__ bp,
    const float* __restrict__ n2g, const float* __restrict__ n2b,
    const float* __restrict__ mw1, const float* __restrict__ mb1,
    const float* __restrict__ mw2, const float* __restrict__ mb2,
    float* __restrict__ o1, float* __restrict__ o2, int obase) {
  int oc = blockIdx.y + obase;
  const float* ao = oc ? ao2 : ao1;
  float* dst      = oc ? o2  : o1;
  __shared__ __align__(16) float wps[1024];
  __shared__ __align__(16) float w1s[2048];
  __shared__ __align__(16) float w2s[2048];
  __shared__ float bps[32], b1s[64], b2s[32], gs[32], bs[32], as[32], bbs[32];
  int t = threadIdx.x;
  for (int i = t; i < 1024; i += 256) wps[i] = wp[i];
  for (int i = t; i < 2048; i += 256) { w1s[i] = mw1[i]; w2s[i] = mw2[i]; }
  if (t < 64) b1s[t] = mb1[t];
  if (t < 32) {
    bps[t] = bp[t]; b2s[t] = mb2[t]; gs[t] = n2g[t]; bs[t] = n2b[t];
    float a = stats[32+t]*ig[t];
    as[t] = a; bbs[t] = ib[t] - stats[t]*a;
  }
  __syncthreads();
  int p = blockIdx.x*256 + t;
  float v[32];
#pragma unroll
  for (int c = 0; c < 32; c++) v[c] = ao[c*HW+p];
  float acc[32];
#pragma unroll
  for (int j = 0; j < 32; j++) acc[j] = bps[j];
#pragma unroll
  for (int c = 0; c < 32; c++) {
    float vc = v[c];
    const float4* w4 = (const float4*)&wps[c*32];
#pragma unroll
    for (int j4 = 0; j4 < 8; j4++) {
      float4 w = w4[j4];
      acc[j4*4+0] += vc*w.x; acc[j4*4+1] += vc*w.y;
      acc[j4*4+2] += vc*w.z; acc[j4*4+3] += vc*w.w;
    }
  }
  // shortcut
  if (oc == 0) {
#pragma unroll
    for (int j = 0; j < 32; j++) acc[j] += x[j*HW+p];
  } else {
#pragma unroll
    for (int j = 0; j < 32; j++) acc[j] += t4[j*HW+p]*as[j] + bbs[j];
  }
  // LN
  float s = 0.f;
#pragma unroll
  for (int j = 0; j < 32; j++) s += acc[j];
  float m = s * 0.03125f;
  float ss = 0.f;
#pragma unroll
  for (int j = 0; j < 32; j++) { float d = acc[j]-m; ss += d*d; }
  float rs = rsqrtf(ss*0.03125f + 1e-5f);
  float r[32];
#pragma unroll
  for (int j = 0; j < 32; j++) r[j] = b2s[j];
#pragma unroll 1
  for (int half = 0; half < 2; half++) {
    float h[32];
#pragma unroll
    for (int k = 0; k < 32; k++) h[k] = b1s[half*32 + k];
#pragma unroll
    for (int c = 0; c < 32; c++) {
      float ln = (acc[c] - m) * rs * gs[c] + bs[c];
      const float4* w4 = (const float4*)&w1s[c*64 + half*32];
#pragma unroll
      for (int k4 = 0; k4 < 8; k4++) {
        float4 w = w4[k4];
        h[k4*4+0] += ln*w.x; h[k4*4+1] += ln*w.y; h[k4*4+2] += ln*w.z; h[k4*4+3] += ln*w.w;
      }
    }
#pragma unroll
    for (int k = 0; k < 32; k++) {
      float xx = h[k];
      float u = 0.7978845608f * (xx + 0.044715f*xx*xx*xx);
      float th = 1.f - 2.f/(1.f + __expf(2.f*u));
      h[k] = 0.5f * xx * (1.f + th);
    }
#pragma unroll
    for (int k = 0; k < 32; k++) {
      float hk = h[k];
      const float4* w4 = (const float4*)&w2s[(half*32 + k)*32];
#pragma unroll
      for (int j4 = 0; j4 < 8; j4++) {
        float4 w = w4[j4];
        r[j4*4+0] += hk*w.x; r[j4*4+1] += hk*w.y; r[j4*4+2] += hk*w.z; r[j4*4+3] += hk*w.w;
      }
    }
  }
#pragma unroll
  for (int j = 0; j < 32; j++) dst[j*HW + p] = acc[j] + r[j];
}

// ---------------- final: out = o1 + o2 + x (o1 aliases out) ----------------
__global__ __launch_bounds__(256) void k_final(
    const float* o1, const float* __restrict__ o2,
    const float* __restrict__ x, float* out) {
  int i = blockIdx.x*256 + threadIdx.x;
  float4 a = ((const float4*)o1)[i];
  float4 b = ((const float4*)o2)[i];
  float4 c = ((const float4*)x)[i];
  float4 r;
  r.x = a.x + b.x + c.x; r.y = a.y + b.y + c.y;
  r.z = a.z + b.z + c.z; r.w = a.w + b.w + c.w;
  ((float4*)out)[i] = r;
}

extern "C" void kernel_launch(void* const* d_in, const int* in_sizes, int n_in,
                              void* d_out, int out_size, void* d_ws, size_t ws_size,
                              hipStream_t stream) {
  const float* x    = (const float*)d_in[0];
  const float* depth= (const float*)d_in[1];
  const int*   rpi  = (const int*)d_in[2];
  const float* cw1  = (const float*)d_in[3],  *cb1 = (const float*)d_in[4];
  const float* cw2  = (const float*)d_in[5],  *cb2 = (const float*)d_in[6];
  const float* cw3  = (const float*)d_in[7],  *cb3 = (const float*)d_in[8];
  const float* cw4  = (const float*)d_in[9],  *cb4 = (const float*)d_in[10];
  const float* in_g = (const float*)d_in[11], *in_b = (const float*)d_in[12];
  const float* n1g  = (const float*)d_in[13], *n1b = (const float*)d_in[14];
  const float* wq   = (const float*)d_in[15], *bq  = (const float*)d_in[16];
  const float* wkv  = (const float*)d_in[17], *bkv = (const float*)d_in[18];
  const float* rpb  = (const float*)d_in[19];
  const float* wp   = (const float*)d_in[20], *bp  = (const float*)d_in[21];
  const float* n2g  = (const float*)d_in[22], *n2b = (const float*)d_in[23];
  const float* mw1  = (const float*)d_in[24], *mb1 = (const float*)d_in[25];
  const float* mw2  = (const float*)d_in[26], *mb2 = (const float*)d_in[27];

  float* W  = (float*)d_ws;
  float* o1 = (float*)d_out;

  bool big = ws_size >= (size_t)85200000;   // merged-OCAB path needs ~85.07 MB

  if (big) {
    float* t4    = W;                    // [0, 2M)
    float* q1    = W + 2097152;          // [2M, 4M)   (t2 aliases first 1M)
    float* q2    = W + 4194304;          // [4M, 6M)   (t3 aliases first 1M)
    float* kv1   = W + 6291456;          // [6M, 10M)
    float* kv2   = W + 10485760;         // [10M, 14M)
    float* ao1   = W + 14680064;         // [14M, 16M)
    float* ao2   = W + 16777216;         // [16M, 18M)
    float* o2    = W + 18874368;         // [18M, 20M)
    float* biasT = W + 20971520;         // 294912
    float* part  = W + 21266432;         // 512
    float* stats = W + 21266944;         // 64
    float* t2 = q1, *t3 = q2;

    k_stem_front<<<256, 256, 0, stream>>>(depth, cw1, cb1, cw2, cb2, t2);
    k_conv3     <<<dim3(256,4), 256, 0, stream>>>(t2, cw3, cb3, t3);
    k_conv4     <<<256, 256, 0, stream>>>(t3, cw4, cb4, t4);
    k_instats1  <<<256, 256, 0, stream>>>(t4, part);
    k_instats2  <<<1,   64,  0, stream>>>(part, stats);
    k_bias      <<<1152,256, 0, stream>>>(rpi, rpb, biasT);
    k_lnmm6     <<<dim3(256,6), 256, 0, stream>>>(x, t4, stats, in_g, in_b, n1g, n1b,
                                                  wq, bq, wkv, bkv, q1, kv1, q2, kv2, 0);
    k_attn      <<<dim3(512,2), 256, 0, stream>>>(q1, kv1, ao1, q2, kv2, ao2, biasT);
    k_projmlp   <<<dim3(256,2), 256, 0, stream>>>(ao1, ao2, x, t4, stats, in_g, in_b,
                                                  wp, bp, n2g, n2b, mw1, mb1, mw2, mb2,
                                                  o1, o2, 0);
    k_final     <<<2048, 256, 0, stream>>>(o1, o2, x, o1);
  } else {
    // serial fallback: proven <= 51.5 MB footprint
    float* t4    = W;                    // [0, 2M)
    float* q1    = W + 2097152;          // [2M, 4M)   (t2 aliases first 1M)
    float* kv1   = W + 4194304;          // [4M, 8M)   (t3 aliases first 1M)
    float* ao    = W + 8388608;          // [8M, 10M)
    float* o2    = W + 10485760;         // [10M, 12M)
    float* biasT = W + 12582912;         // 294912
    float* part  = W + 12877824;         // 512
    float* stats = W + 12878336;         // 64
    float* t2 = q1, *t3 = kv1;

    k_stem_front<<<256, 256, 0, stream>>>(depth, cw1, cb1, cw2, cb2, t2);
    k_conv3     <<<dim3(256,4), 256, 0, stream>>>(t2, cw3, cb3, t3);
    k_conv4     <<<256, 256, 0, stream>>>(t3, cw4, cb4, t4);
    k_instats1  <<<256, 256, 0, stream>>>(t4, part);
    k_instats2  <<<1,   64,  0, stream>>>(part, stats);
    k_bias      <<<1152,256, 0, stream>>>(rpi, rpb, biasT);

    k_lnmm6     <<<dim3(256,3), 256, 0, stream>>>(x, t4, stats, in_g, in_b, n1g, n1b,
                                                  wq, bq, wkv, bkv, q1, kv1, q1, kv1, 0);
    k_attn      <<<dim3(512,1), 256, 0, stream>>>(q1, kv1, ao, q1, kv1, ao, biasT);
    k_projmlp   <<<dim3(256,1), 256, 0, stream>>>(ao, ao, x, t4, stats, in_g, in_b,
                                                  wp, bp, n2g, n2b, mw1, mb1, mw2, mb2,
                                                  o1, o2, 0);
    k_lnmm6     <<<dim3(256,3), 256, 0, stream>>>(x, t4, stats, in_g, in_b, n1g, n1b,
                                                  wq, bq, wkv, bkv, q1, kv1, q1, kv1, 3);
    k_attn      <<<dim3(512,1), 256, 0, stream>>>(q1, kv1, ao, q1, kv1, ao, biasT);
    k_projmlp   <<<dim3(256,1), 256, 0, stream>>>(ao, ao, x, t4, stats, in_g, in_b,
                                                  wp, bp, n2g, n2b, mw1, mb1, mw2, mb2,
                                                  o1, o2, 1);
    k_final     <<<2048, 256, 0, stream>>>(o1, o2, x, o1);
  }
}